// Round 3
// baseline (15122.234 us; speedup 1.0000x reference)
//
#include <hip/hip_runtime.h>
#include <hip/hip_bf16.h>
#include <hip/hip_cooperative_groups.h>

namespace cg = cooperative_groups;

typedef __attribute__((ext_vector_type(8))) short short8;
typedef __attribute__((ext_vector_type(4))) float floatx4;
typedef __hip_bfloat16 bf16;

#define MFMA16(a,b,c) __builtin_amdgcn_mfma_f32_16x16x32_bf16((a),(b),(c),0,0,0)

__device__ __forceinline__ short8 ldf(const bf16* p){ return *(const short8*)p; }
__device__ __forceinline__ float fsig(float x){ return 1.f/(1.f+__expf(-x)); }
__device__ __forceinline__ float ftanh(float x){
  float c = fminf(fmaxf(x,-15.f),15.f);
  float e = __expf(2.f*c);
  return (e-1.f)/(e+1.f);
}

typedef __attribute__((address_space(1))) void gvoid;
typedef __attribute__((address_space(3))) void lvoid;
// async global->LDS, 16B per lane; LDS dest = uniform base + lane*16
__device__ __forceinline__ void stage16(const bf16* g, bf16* l){
  __builtin_amdgcn_global_load_lds((gvoid*)g, (lvoid*)l, 16, 0, 0);
}

// ---------------- weight prep: fp32 [R][C] -> bf16 [C][R] ----------------
__global__ __launch_bounds__(256) void k_transpose(const float* __restrict__ in,
                                                   bf16* __restrict__ out, int R, int C){
  __shared__ float t[32][33];
  int bc = blockIdx.x*32, br = blockIdx.y*32;
  int tx = threadIdx.x & 31, ty = threadIdx.x >> 5;
  #pragma unroll
  for (int i=0;i<32;i+=8) t[ty+i][tx] = in[(size_t)(br+ty+i)*C + bc+tx];
  __syncthreads();
  #pragma unroll
  for (int i=0;i<32;i+=8) out[(size_t)(bc+ty+i)*R + br+tx] = __float2bfloat16(t[tx][ty+i]);
}

__global__ __launch_bounds__(256) void k_cast(const float* __restrict__ in, bf16* __restrict__ out, int n){
  int i = blockIdx.x*256+threadIdx.x;
  if (i<n) out[i] = __float2bfloat16(in[i]);
}

__global__ __launch_bounds__(256) void k_cast_state(const float* __restrict__ st, bf16* __restrict__ pin){
  int i = blockIdx.x*256+threadIdx.x; // 16384
  int r = i >> 6, c = i & 63;
  pin[r*192 + c] = __float2bfloat16(st[i]);
}

__global__ __launch_bounds__(256) void k_acth1(const float* __restrict__ act,
                                               const float* __restrict__ w1,
                                               const float* __restrict__ b1,
                                               bf16* __restrict__ H1){
  int idx = blockIdx.x*256 + threadIdx.x;
  int c = idx & 511; int r = idx >> 9;
  int t = r >> 8, b = r & 255;
  const float* a = act + (b*64 + t)*6;
  float s = b1[c];
  #pragma unroll
  for (int i=0;i<6;i++) s += a[i]*w1[i*512+c];
  H1[r*512+c] = __float2bfloat16(ftanh(s));
}

// ---------------- generic GEMM (setup path only, small shapes) ----------------
__global__ __launch_bounds__(256) void k_gemm16(
  const bf16* __restrict__ A, int sA,
  const bf16* __restrict__ Bt,
  const float* __restrict__ bias,
  bf16* __restrict__ out, int sO, int oO,
  int K, int mode)
{
  int lane = threadIdx.x & 63, wave = threadIdx.x >> 6;
  int lr = lane & 15, lq = lane >> 4;
  int j0 = blockIdx.x*64 + wave*16;
  int m0 = blockIdx.y*16;
  const bf16* Ap = A + (m0+lr)*sA + lq*8;
  const bf16* Bp = Bt + (j0+lr)*K + lq*8;
  floatx4 acc = {0.f,0.f,0.f,0.f};
  #pragma unroll 4
  for (int kb=0; kb<K; kb+=32){
    short8 a = ldf(Ap+kb);
    short8 b = ldf(Bp+kb);
    acc = MFMA16(a, b, acc);
  }
  #pragma unroll
  for (int i=0;i<4;i++){
    int m = m0 + lq*4 + i, j = j0 + lr;
    float v = acc[i] + bias[j];
    if (mode) v = ftanh(v);
    out[m*sO + oO + j] = __float2bfloat16(v);
  }
}

// ---------------- gaussian head (setup: z0) ----------------
__global__ __launch_bounds__(256) void k_gauss(
  const bf16* __restrict__ A, const bf16* __restrict__ Bt,
  const float* __restrict__ bias, const float* __restrict__ eps,
  bf16* __restrict__ out, int K)
{
  int lane = threadIdx.x & 63, wave = threadIdx.x >> 6;
  int lr = lane & 15, lq = lane >> 4;
  int j0 = blockIdx.x*64 + wave*16;
  int m0 = blockIdx.y*16;
  const bf16* Ap = A + (m0+lr)*K + lq*8;
  const bf16* Bm = Bt + (j0+lr)*K + lq*8;
  const bf16* Bl = Bt + (j0+1024+lr)*K + lq*8;
  floatx4 aM = {0.f,0.f,0.f,0.f}, aL = {0.f,0.f,0.f,0.f};
  #pragma unroll 4
  for (int kb=0;kb<K;kb+=32){
    short8 a = ldf(Ap+kb);
    aM = MFMA16(a, ldf(Bm+kb), aM);
    aL = MFMA16(a, ldf(Bl+kb), aL);
  }
  #pragma unroll
  for (int i=0;i<4;i++){
    int m = m0+lq*4+i, j = j0+lr;
    float z = aM[i] + bias[j] + __expf(aL[i] + bias[1024+j]) * eps[m*1024 + j];
    out[m*1024+j] = __float2bfloat16(z);
  }
}

// ---------------- AE gemm: 128x128 LDS tile ----------------
// AEb = H1 @ amlp_w2 + b2 : M=16384, N=512, K=512. grid (4,128).
__global__ __launch_bounds__(256) void k_aev2(
  const bf16* __restrict__ A, const bf16* __restrict__ W,
  const float* __restrict__ bias, bf16* __restrict__ Out)
{
  __shared__ __align__(16) bf16 As[128*32];
  __shared__ __align__(16) bf16 Bs[128*32];
  const int tid = threadIdx.x, lane = tid & 63, w = tid >> 6;
  const int lr = lane & 15, lq = lane >> 4;
  const int mh = (w & 1) * 64, jh = (w >> 1) * 64;
  const int m0 = blockIdx.y * 128, j0 = blockIdx.x * 128;
  const int cA0 = w*128 + lane,      cA1 = w*128 + 64 + lane;
  const int r0 = cA0>>2, o0 = (cA0&3)*8, r1 = cA1>>2, o1 = (cA1&3)*8;
  bf16* lA0 = As + (w*2+0)*512; bf16* lA1 = As + (w*2+1)*512;
  bf16* lB0 = Bs + (w*2+0)*512; bf16* lB1 = Bs + (w*2+1)*512;
  floatx4 acc[4][4] = {};
  for (int kb=0; kb<512; kb+=32){
    stage16(A + (size_t)(m0+r0)*512 + kb + o0, lA0);
    stage16(A + (size_t)(m0+r1)*512 + kb + o1, lA1);
    stage16(W + (size_t)(j0+r0)*512 + kb + o0, lB0);
    stage16(W + (size_t)(j0+r1)*512 + kb + o1, lB1);
    __syncthreads();
    short8 af[4], bfr[4];
    #pragma unroll
    for (int f=0; f<4; f++){
      af[f]  = *(const short8*)&As[(mh + f*16 + lr)*32 + lq*8];
      bfr[f] = *(const short8*)&Bs[(jh + f*16 + lr)*32 + lq*8];
    }
    #pragma unroll
    for (int mf=0; mf<4; mf++)
      #pragma unroll
      for (int jf=0; jf<4; jf++)
        acc[mf][jf] = MFMA16(af[mf], bfr[jf], acc[mf][jf]);
    __syncthreads();
  }
  #pragma unroll
  for (int mf=0; mf<4; mf++)
    #pragma unroll
    for (int jf=0; jf<4; jf++)
      #pragma unroll
      for (int i=0; i<4; i++){
        int m = m0 + mh + mf*16 + lq*4 + i;
        int j = j0 + jh + jf*16 + lr;
        Out[(size_t)m*512 + j] = __float2bfloat16(acc[mf][jf][i] + bias[j]);
      }
}

// ---------------- per-step scan kernels (verified fallback path) ----------------
__global__ __launch_bounds__(256) void k_gru2(
  const bf16* __restrict__ Z, const bf16* __restrict__ H, const bf16* __restrict__ AE,
  const bf16* __restrict__ WzT, const bf16* __restrict__ WhT, const bf16* __restrict__ WaT,
  const float* __restrict__ bih, const float* __restrict__ bhh,
  bf16* __restrict__ Hn)
{
  __shared__ float red[4][4][64][4];
  const int tid = threadIdx.x, lane = tid & 63, w = tid >> 6;
  const int lr = lane & 15, lq = lane >> 4;
  const int j0 = (blockIdx.x & 63) * 16, m0 = (blockIdx.x >> 6) * 16;
  const int jl = j0 + lr;
  const int c0 = w*640, c1 = c0+640;
  floatx4 R={},U={},NX={},NH={};
  {
    int hi = c1 < 1024 ? c1 : 1024;
    for (int k=c0; k<hi; k+=32){
      short8 a = ldf(Z + (m0+lr)*1024 + k + lq*8);
      const bf16* bp = WzT + k + lq*8;
      R = MFMA16(a, ldf(bp + (size_t)jl*1024), R);
      U = MFMA16(a, ldf(bp + (size_t)(jl+1024)*1024), U);
      NX= MFMA16(a, ldf(bp + (size_t)(jl+2048)*1024), NX);
    }
  }
  {
    int lo = c0 > 1024 ? c0 : 1024;
    int hi = c1 < 1536 ? c1 : 1536;
    for (int k=lo; k<hi; k+=32){
      int kk = k - 1024;
      short8 a = ldf(AE + (m0+lr)*512 + kk + lq*8);
      const bf16* bp = WaT + kk + lq*8;
      R = MFMA16(a, ldf(bp + (size_t)jl*512), R);
      U = MFMA16(a, ldf(bp + (size_t)(jl+1024)*512), U);
      NX= MFMA16(a, ldf(bp + (size_t)(jl+2048)*512), NX);
    }
  }
  {
    int lo = c0 > 1536 ? c0 : 1536;
    for (int k=lo; k<c1; k+=32){
      int kk = k - 1536;
      short8 a = ldf(H + (m0+lr)*1024 + kk + lq*8);
      const bf16* bp = WhT + kk + lq*8;
      R = MFMA16(a, ldf(bp + (size_t)jl*1024), R);
      U = MFMA16(a, ldf(bp + (size_t)(jl+1024)*1024), U);
      NH= MFMA16(a, ldf(bp + (size_t)(jl+2048)*1024), NH);
    }
  }
  *(floatx4*)&red[w][0][lane][0]=R;
  *(floatx4*)&red[w][1][lane][0]=U;
  *(floatx4*)&red[w][2][lane][0]=NX;
  *(floatx4*)&red[w][3][lane][0]=NH;
  __syncthreads();
  if (w==0){
    floatx4 sR={},sU={},sNX={},sNH={};
    #pragma unroll
    for (int ww=0;ww<4;ww++){
      sR += *(const floatx4*)&red[ww][0][lane][0];
      sU += *(const floatx4*)&red[ww][1][lane][0];
      sNX+= *(const floatx4*)&red[ww][2][lane][0];
      sNH+= *(const floatx4*)&red[ww][3][lane][0];
    }
    float bR = bih[jl]+bhh[jl];
    float bU = bih[1024+jl]+bhh[1024+jl];
    float bX = bih[2048+jl], bH = bhh[2048+jl];
    #pragma unroll
    for (int i=0;i<4;i++){
      int m = m0 + lq*4 + i;
      float r = fsig(sR[i]+bR);
      float u = fsig(sU[i]+bU);
      float n = ftanh(sNX[i]+bX + r*(sNH[i]+bH));
      float h = __bfloat162float(H[m*1024+jl]);
      Hn[m*1024+jl] = __float2bfloat16((1.f-u)*n + u*h);
    }
  }
}

__global__ __launch_bounds__(256) void k_lsd1(
  const bf16* __restrict__ Hn, const bf16* __restrict__ Lw1,
  const float* __restrict__ Lb1, bf16* __restrict__ X)
{
  __shared__ float red[4][64][4];
  const int tid = threadIdx.x, lane = tid & 63, w = tid >> 6;
  const int lr = lane & 15, lq = lane >> 4;
  const int j0 = (blockIdx.x & 63) * 16, m0 = (blockIdx.x >> 6) * 16;
  const int jl = j0 + lr;
  floatx4 C={};
  const bf16* Ap = Hn + (m0+lr)*1024 + lq*8;
  const bf16* Bp = Lw1 + (size_t)jl*1024 + lq*8;
  #pragma unroll
  for (int k=w*256; k<w*256+256; k+=32)
    C = MFMA16(ldf(Ap+k), ldf(Bp+k), C);
  *(floatx4*)&red[w][lane][0] = C;
  __syncthreads();
  if (w==0){
    floatx4 s={};
    #pragma unroll
    for (int ww=0;ww<4;ww++) s += *(const floatx4*)&red[ww][lane][0];
    float bb = Lb1[jl];
    #pragma unroll
    for (int i=0;i<4;i++){
      int m = m0 + lq*4 + i;
      X[m*1024+jl] = __float2bfloat16(ftanh(s[i]+bb));
    }
  }
}

__global__ __launch_bounds__(256) void k_lsd2(
  const bf16* __restrict__ X, const bf16* __restrict__ Lw2,
  const float* __restrict__ Lb2, const float* __restrict__ eps,
  bf16* __restrict__ Zn)
{
  __shared__ float red[4][2][64][4];
  const int tid = threadIdx.x, lane = tid & 63, w = tid >> 6;
  const int lr = lane & 15, lq = lane >> 4;
  const int j0 = (blockIdx.x & 63) * 16, m0 = (blockIdx.x >> 6) * 16;
  const int jl = j0 + lr;
  floatx4 M={}, L={};
  const bf16* Ap = X + (m0+lr)*1024 + lq*8;
  const bf16* Bm = Lw2 + (size_t)jl*1024 + lq*8;
  const bf16* Bl = Lw2 + (size_t)(1024+jl)*1024 + lq*8;
  #pragma unroll
  for (int k=w*256; k<w*256+256; k+=32){
    short8 a = ldf(Ap+k);
    M = MFMA16(a, ldf(Bm+k), M);
    L = MFMA16(a, ldf(Bl+k), L);
  }
  *(floatx4*)&red[w][0][lane][0] = M;
  *(floatx4*)&red[w][1][lane][0] = L;
  __syncthreads();
  if (w==0){
    floatx4 sM={}, sL={};
    #pragma unroll
    for (int ww=0;ww<4;ww++){
      sM += *(const floatx4*)&red[ww][0][lane][0];
      sL += *(const floatx4*)&red[ww][1][lane][0];
    }
    float bmu = Lb2[jl], bls = Lb2[1024+jl];
    #pragma unroll
    for (int i=0;i<4;i++){
      int m = m0 + lq*4 + i;
      float z = sM[i]+bmu + __expf(sL[i]+bls) * eps[m*1024+jl];
      Zn[m*1024+jl] = __float2bfloat16(z);
    }
  }
}

// ---------------- persistent cooperative scan, v3 (flex grid) ----------------
// grid = 64*MB blocks (MB in {8,16}), block b: jt = b&63, m-tiles strided
// mt = (b>>6), (b>>6)+MB, ... < 16. Grid size is chosen on the HOST from an
// occupancy query so the cooperative launch is valid BY CONSTRUCTION (round 2
// failed: 1024 blocks at exactly 4/CU capacity was rejected and the error was
// ignored). Per phase this is the verified baseline decomposition (16m x 16j
// tile, 4-way wave K-split + LDS reduce); grid.sync() replaces 191 launches.
__global__ __launch_bounds__(256, 4) void k_scan(
  bf16* __restrict__ Zbuf, bf16* __restrict__ Hbuf, const bf16* __restrict__ AEb,
  const bf16* __restrict__ WzT, const bf16* __restrict__ WhT, const bf16* __restrict__ WaT,
  const float* __restrict__ gbih, const float* __restrict__ gbhh,
  const bf16* __restrict__ Lw1T, const float* __restrict__ Lb1,
  const bf16* __restrict__ Lw2T, const float* __restrict__ Lb2,
  const float* __restrict__ epss, bf16* __restrict__ X)
{
  __shared__ float red[4][4][64][4];
  const int tid = threadIdx.x, lane = tid & 63, w = tid >> 6;
  const int lr = lane & 15, lq = lane >> 4;
  const int jt = blockIdx.x & 63, mt0 = blockIdx.x >> 6;
  const int MB = gridDim.x >> 6;
  const int jl = jt * 16 + lr;

  // t-invariant, j-dependent weight pointers & biases
  const bf16* BzR = WzT + (size_t)jl*1024 + lq*8;
  const bf16* BzU = WzT + (size_t)(jl+1024)*1024 + lq*8;
  const bf16* BzN = WzT + (size_t)(jl+2048)*1024 + lq*8;
  const bf16* BaR = WaT + (size_t)jl*512 + lq*8;
  const bf16* BaU = WaT + (size_t)(jl+1024)*512 + lq*8;
  const bf16* BaN = WaT + (size_t)(jl+2048)*512 + lq*8;
  const bf16* BhR = WhT + (size_t)jl*1024 + lq*8;
  const bf16* BhU = WhT + (size_t)(jl+1024)*1024 + lq*8;
  const bf16* BhN = WhT + (size_t)(jl+2048)*1024 + lq*8;
  const bf16* B1  = Lw1T + (size_t)jl*1024 + lq*8;
  const bf16* B2m = Lw2T + (size_t)jl*1024 + lq*8;
  const bf16* B2l = Lw2T + (size_t)(1024+jl)*1024 + lq*8;
  const float bR = gbih[jl]      + gbhh[jl];
  const float bU = gbih[1024+jl] + gbhh[1024+jl];
  const float bX = gbih[2048+jl], bH = gbhh[2048+jl];
  const float bb1 = Lb1[jl];
  const float bmu = Lb2[jl], bls = Lb2[1024+jl];

  cg::grid_group grid = cg::this_grid();

  for (int t=0; t<64; t++){
    const bf16* Zt  = Zbuf + (size_t)t*262144;
    const bf16* Ht  = Hbuf + (size_t)t*262144;
    bf16*       Htn = Hbuf + (size_t)(t+1)*262144;
    bf16*       Ztn = Zbuf + (size_t)(t+1)*262144;
    const bf16* AE  = AEb  + (size_t)t*131072;

    // ---- phase G: GRU cell (wave K-slice 640 of concat-K 2560) ----
    for (int mt = mt0; mt < 16; mt += MB){
      const int m0 = mt * 16;
      const int c0 = w*640, c1 = c0+640;
      floatx4 R={},U={},NX={},NH={};
      {
        int hi = c1 < 1024 ? c1 : 1024;
        const bf16* Ap = Zt + (size_t)(m0+lr)*1024 + lq*8;
        for (int k=c0; k<hi; k+=32){
          short8 a = ldf(Ap + k);
          R = MFMA16(a, ldf(BzR+k), R);
          U = MFMA16(a, ldf(BzU+k), U);
          NX= MFMA16(a, ldf(BzN+k), NX);
        }
      }
      {
        int lo = c0 > 1024 ? c0 : 1024;
        int hi = c1 < 1536 ? c1 : 1536;
        const bf16* Ap = AE + (size_t)(m0+lr)*512 + lq*8;
        for (int k=lo; k<hi; k+=32){
          int kk = k - 1024;
          short8 a = ldf(Ap + kk);
          R = MFMA16(a, ldf(BaR+kk), R);
          U = MFMA16(a, ldf(BaU+kk), U);
          NX= MFMA16(a, ldf(BaN+kk), NX);
        }
      }
      {
        int lo = c0 > 1536 ? c0 : 1536;
        const bf16* Ap = Ht + (size_t)(m0+lr)*1024 + lq*8;
        for (int k=lo; k<c1; k+=32){
          int kk = k - 1536;
          short8 a = ldf(Ap + kk);
          R = MFMA16(a, ldf(BhR+kk), R);
          U = MFMA16(a, ldf(BhU+kk), U);
          NH= MFMA16(a, ldf(BhN+kk), NH);
        }
      }
      *(floatx4*)&red[w][0][lane][0]=R;
      *(floatx4*)&red[w][1][lane][0]=U;
      *(floatx4*)&red[w][2][lane][0]=NX;
      *(floatx4*)&red[w][3][lane][0]=NH;
      __syncthreads();
      if (w==0){
        floatx4 sR={},sU={},sNX={},sNH={};
        #pragma unroll
        for (int ww=0;ww<4;ww++){
          sR += *(const floatx4*)&red[ww][0][lane][0];
          sU += *(const floatx4*)&red[ww][1][lane][0];
          sNX+= *(const floatx4*)&red[ww][2][lane][0];
          sNH+= *(const floatx4*)&red[ww][3][lane][0];
        }
        #pragma unroll
        for (int i=0;i<4;i++){
          int m = m0 + lq*4 + i;
          float r = fsig(sR[i]+bR);
          float u = fsig(sU[i]+bU);
          float n = ftanh(sNX[i]+bX + r*(sNH[i]+bH));
          float h = __bfloat162float(Ht[m*1024+jl]);
          Htn[m*1024+jl] = __float2bfloat16((1.f-u)*n + u*h);
        }
      }
      __syncthreads();   // protect red before next mt iteration
    }
    grid.sync();

    // ---- phase L1: X = tanh(Hn @ Lw1 + b1), wave K-slice 256 ----
    for (int mt = mt0; mt < 16; mt += MB){
      const int m0 = mt * 16;
      floatx4 C={};
      const bf16* Ap = Htn + (size_t)(m0+lr)*1024 + lq*8;
      #pragma unroll
      for (int k=w*256; k<w*256+256; k+=32)
        C = MFMA16(ldf(Ap+k), ldf(B1+k), C);
      *(floatx4*)&red[w][0][lane][0] = C;
      __syncthreads();
      if (w==0){
        floatx4 s={};
        #pragma unroll
        for (int ww=0;ww<4;ww++) s += *(const floatx4*)&red[ww][0][lane][0];
        #pragma unroll
        for (int i=0;i<4;i++){
          int m = m0 + lq*4 + i;
          X[m*1024+jl] = __float2bfloat16(ftanh(s[i]+bb1));
        }
      }
      __syncthreads();
    }
    grid.sync();

    // ---- phase L2: Zn = mu + exp(ls)*eps, wave K-slice 256, 2 heads ----
    for (int mt = mt0; mt < 16; mt += MB){
      const int m0 = mt * 16;
      floatx4 M={}, L={};
      const bf16* Ap = X + (size_t)(m0+lr)*1024 + lq*8;
      #pragma unroll
      for (int k=w*256; k<w*256+256; k+=32){
        short8 a = ldf(Ap+k);
        M = MFMA16(a, ldf(B2m+k), M);
        L = MFMA16(a, ldf(B2l+k), L);
      }
      *(floatx4*)&red[w][0][lane][0] = M;
      *(floatx4*)&red[w][1][lane][0] = L;
      __syncthreads();
      if (w==0){
        floatx4 sM={}, sL={};
        #pragma unroll
        for (int ww=0;ww<4;ww++){
          sM += *(const floatx4*)&red[ww][0][lane][0];
          sL += *(const floatx4*)&red[ww][1][lane][0];
        }
        #pragma unroll
        for (int i=0;i<4;i++){
          int m = m0 + lq*4 + i;
          float z = sM[i]+bmu + __expf(sL[i]+bls) * epss[(size_t)t*262144 + m*1024+jl];
          Ztn[m*1024+jl] = __float2bfloat16(z);
        }
      }
      __syncthreads();
    }
    grid.sync();
  }
}

// ---------------- decode: 128x128 LDS-tiled GEMM with global_load_lds ----------------
// Y = tanh([Zb|Hb] @ W^T + bias): M=16384, N=1024, K=2048(2 segs). grid (8,128).
__global__ __launch_bounds__(256) void k_dec1v2(
  const bf16* __restrict__ Zb, const bf16* __restrict__ Hb,
  const bf16* __restrict__ W, const float* __restrict__ bias,
  bf16* __restrict__ Y)
{
  __shared__ __align__(16) bf16 As[128*32];
  __shared__ __align__(16) bf16 Bs[128*32];
  const int tid = threadIdx.x, lane = tid & 63, w = tid >> 6;
  const int lr = lane & 15, lq = lane >> 4;
  const int mh = (w & 1) * 64, jh = (w >> 1) * 64;
  const int m0 = blockIdx.y * 128, j0 = blockIdx.x * 128;
  const int cA0 = w*128 + lane,      cA1 = w*128 + 64 + lane;
  const int r0 = cA0>>2, o0 = (cA0&3)*8, r1 = cA1>>2, o1 = (cA1&3)*8;
  bf16* lA0 = As + (w*2+0)*512; bf16* lA1 = As + (w*2+1)*512;
  bf16* lB0 = Bs + (w*2+0)*512; bf16* lB1 = Bs + (w*2+1)*512;
  floatx4 acc[4][4] = {};
  const bf16* Aseg[2] = { Zb + 256*1024, Hb + 256*1024 };
  #pragma unroll
  for (int seg=0; seg<2; seg++){
    const bf16* A = Aseg[seg];
    const bf16* Wb = W + seg*1024;
    for (int kb=0; kb<1024; kb+=32){
      stage16(A  + (size_t)(m0+r0)*1024 + kb + o0, lA0);
      stage16(A  + (size_t)(m0+r1)*1024 + kb + o1, lA1);
      stage16(Wb + (size_t)(j0+r0)*2048 + kb + o0, lB0);
      stage16(Wb + (size_t)(j0+r1)*2048 + kb + o1, lB1);
      __syncthreads();
      short8 af[4], bfr[4];
      #pragma unroll
      for (int f=0; f<4; f++){
        af[f]  = *(const short8*)&As[(mh + f*16 + lr)*32 + lq*8];
        bfr[f] = *(const short8*)&Bs[(jh + f*16 + lr)*32 + lq*8];
      }
      #pragma unroll
      for (int mf=0; mf<4; mf++)
        #pragma unroll
        for (int jf=0; jf<4; jf++)
          acc[mf][jf] = MFMA16(af[mf], bfr[jf], acc[mf][jf]);
      __syncthreads();
    }
  }
  #pragma unroll
  for (int mf=0; mf<4; mf++)
    #pragma unroll
    for (int jf=0; jf<4; jf++)
      #pragma unroll
      for (int i=0; i<4; i++){
        int m = m0 + mh + mf*16 + lq*4 + i;
        int j = j0 + jh + jf*16 + lr;
        Y[(size_t)m*1024 + j] = __float2bfloat16(ftanh(acc[mf][jf][i] + bias[j]));
      }
}

// obs_pred = Y1 @ dec_w2 + b -> out[b][t][0:512]: M=16384,N=512,K=1024. grid (4,128).
__global__ __launch_bounds__(256) void k_out1v2(
  const bf16* __restrict__ Yb, const bf16* __restrict__ W,
  const float* __restrict__ bias, float* __restrict__ out)
{
  __shared__ __align__(16) bf16 As[128*32];
  __shared__ __align__(16) bf16 Bs[128*32];
  const int tid = threadIdx.x, lane = tid & 63, w = tid >> 6;
  const int lr = lane & 15, lq = lane >> 4;
  const int mh = (w & 1) * 64, jh = (w >> 1) * 64;
  const int m0 = blockIdx.y * 128, j0 = blockIdx.x * 128;
  const int cA0 = w*128 + lane,      cA1 = w*128 + 64 + lane;
  const int r0 = cA0>>2, o0 = (cA0&3)*8, r1 = cA1>>2, o1 = (cA1&3)*8;
  bf16* lA0 = As + (w*2+0)*512; bf16* lA1 = As + (w*2+1)*512;
  bf16* lB0 = Bs + (w*2+0)*512; bf16* lB1 = Bs + (w*2+1)*512;
  floatx4 acc[4][4] = {};
  for (int kb=0; kb<1024; kb+=32){
    stage16(Yb + (size_t)(m0+r0)*1024 + kb + o0, lA0);
    stage16(Yb + (size_t)(m0+r1)*1024 + kb + o1, lA1);
    stage16(W  + (size_t)(j0+r0)*1024 + kb + o0, lB0);
    stage16(W  + (size_t)(j0+r1)*1024 + kb + o1, lB1);
    __syncthreads();
    short8 af[4], bfr[4];
    #pragma unroll
    for (int f=0; f<4; f++){
      af[f]  = *(const short8*)&As[(mh + f*16 + lr)*32 + lq*8];
      bfr[f] = *(const short8*)&Bs[(jh + f*16 + lr)*32 + lq*8];
    }
    #pragma unroll
    for (int mf=0; mf<4; mf++)
      #pragma unroll
      for (int jf=0; jf<4; jf++)
        acc[mf][jf] = MFMA16(af[mf], bfr[jf], acc[mf][jf]);
    __syncthreads();
  }
  #pragma unroll
  for (int mf=0; mf<4; mf++)
    #pragma unroll
    for (int jf=0; jf<4; jf++)
      #pragma unroll
      for (int i=0; i<4; i++){
        int m = m0 + mh + mf*16 + lq*4 + i;
        int j = j0 + jh + jf*16 + lr;
        int b = m & 255, t = m >> 8;
        out[(size_t)b*40960 + t*640 + j] = acc[mf][jf][i] + bias[j];
      }
}

// state decoder: din @ sd_w + b -> out[...,512:576]=mu, [...,576:640]=exp(ls)
__global__ __launch_bounds__(256) void k_sd(
  const bf16* __restrict__ Zb, const bf16* __restrict__ Hb,
  const bf16* __restrict__ W, const float* __restrict__ bias,
  float* __restrict__ out)
{
  int lane = threadIdx.x & 63, wave = threadIdx.x >> 6;
  int lr = lane & 15, lq = lane >> 4;
  int m0 = blockIdx.x * 32;
  int j0 = wave * 16;
  floatx4 aM[2] = {}, aL[2] = {};
  const bf16* Az = Zb + 256*1024;
  const bf16* Ah = Hb + 256*1024;
  #pragma unroll 2
  for (int kb=0; kb<1024; kb+=32){
    short8 a0 = ldf(Az + (m0+lr)*1024 + kb + lq*8);
    short8 a1 = ldf(Az + (m0+16+lr)*1024 + kb + lq*8);
    short8 bm = ldf(W + (size_t)(j0+lr)*2048 + kb + lq*8);
    short8 bl = ldf(W + (size_t)(j0+64+lr)*2048 + kb + lq*8);
    aM[0] = MFMA16(a0,bm,aM[0]); aM[1] = MFMA16(a1,bm,aM[1]);
    aL[0] = MFMA16(a0,bl,aL[0]); aL[1] = MFMA16(a1,bl,aL[1]);
  }
  #pragma unroll 2
  for (int kb=0; kb<1024; kb+=32){
    short8 a0 = ldf(Ah + (m0+lr)*1024 + kb + lq*8);
    short8 a1 = ldf(Ah + (m0+16+lr)*1024 + kb + lq*8);
    short8 bm = ldf(W + (size_t)(j0+lr)*2048 + 1024 + kb + lq*8);
    short8 bl = ldf(W + (size_t)(j0+64+lr)*2048 + 1024 + kb + lq*8);
    aM[0] = MFMA16(a0,bm,aM[0]); aM[1] = MFMA16(a1,bm,aM[1]);
    aL[0] = MFMA16(a0,bl,aL[0]); aL[1] = MFMA16(a1,bl,aL[1]);
  }
  #pragma unroll
  for (int rf=0;rf<2;rf++)
    #pragma unroll
    for (int i=0;i<4;i++){
      int m = m0 + rf*16 + lq*4 + i;
      int j = j0 + lr;
      int b = m & 255, t = m >> 8;
      out[b*40960 + t*640 + 512 + j] = aM[rf][i] + bias[j];
      out[b*40960 + t*640 + 576 + j] = __expf(aL[rf][i] + bias[64+j]);
    }
}

extern "C" void kernel_launch(void* const* d_in, const int* in_sizes, int n_in,
                              void* d_out, int out_size, void* d_ws, size_t ws_size,
                              hipStream_t stream)
{
  const float* obs    = (const float*)d_in[0];
  const float* state  = (const float*)d_in[1];
  const float* act    = (const float*)d_in[2];
  const float* eps0   = (const float*)d_in[3];
  const float* epss   = (const float*)d_in[4];
  const float* enc_w1 = (const float*)d_in[5];  const float* enc_b1 = (const float*)d_in[6];
  const float* enc_w2 = (const float*)d_in[7];  const float* enc_b2 = (const float*)d_in[8];
  const float* post_w1= (const float*)d_in[9];  const float* post_b1= (const float*)d_in[10];
  const float* post_w2= (const float*)d_in[11]; const float* post_b2= (const float*)d_in[12];
  const float* amlp_w1= (const float*)d_in[13]; const float* amlp_b1= (const float*)d_in[14];
  const float* amlp_w2= (const float*)d_in[15]; const float* amlp_b2= (const float*)d_in[16];
  const float* gwih   = (const float*)d_in[17];
  const float* gwhh   = (const float*)d_in[18];
  const float* gbih   = (const float*)d_in[19];
  const float* gbhh   = (const float*)d_in[20];
  const float* lsd_w1 = (const float*)d_in[21]; const float* lsd_b1 = (const float*)d_in[22];
  const float* lsd_w2 = (const float*)d_in[23]; const float* lsd_b2 = (const float*)d_in[24];
  const float* dec_w1 = (const float*)d_in[25]; const float* dec_b1 = (const float*)d_in[26];
  const float* dec_w2 = (const float*)d_in[27]; const float* dec_b2 = (const float*)d_in[28];
  const float* sd_w   = (const float*)d_in[29]; const float* sd_b   = (const float*)d_in[30];
  float* out = (float*)d_out;

  char* w = (char*)d_ws;
  size_t off = 0;
  auto alloc = [&](size_t elems)->bf16* {
    bf16* p = (bf16*)(w + off);
    off += ((elems*2 + 255)/256)*256;
    return p;
  };
  bf16* WzT      = alloc((size_t)3072*1024);
  bf16* WhT      = alloc((size_t)3072*1024);
  bf16* WaT      = alloc((size_t)3072*512);
  bf16* lsd_w1T  = alloc((size_t)1024*1024);
  bf16* lsd_w2T  = alloc((size_t)2048*1024);
  bf16* dec_w1T  = alloc((size_t)1024*2048);
  bf16* dec_w2T  = alloc((size_t)512*1024);
  bf16* sd_wT    = alloc((size_t)128*2048);
  bf16* enc_w1T  = alloc((size_t)512*512);
  bf16* enc_w2T  = alloc((size_t)256*512);
  bf16* post_w1sT= alloc((size_t)1024*192);
  bf16* post_w2T = alloc((size_t)2048*1024);
  bf16* amlp_w2T = alloc((size_t)512*512);
  bf16* obsb     = alloc((size_t)256*512);
  bf16* E1       = alloc((size_t)256*512);
  bf16* PIN      = alloc((size_t)256*192);
  bf16* P1       = alloc((size_t)256*1024);
  bf16* X        = alloc((size_t)256*1024);
  bf16* Zbuf     = alloc((size_t)65*256*1024);
  bf16* Hbuf     = alloc((size_t)65*256*1024);
  bf16* AEb      = alloc((size_t)16384*512);
  bf16* Y1       = alloc((size_t)16384*1024);
  bf16* H1       = Y1;   // H1 (16 MiB) dead before Y1 is written

  // --- weight prep ---
  #define TP(src, dst, R, C) k_transpose<<<dim3((C)/32,(R)/32),256,0,stream>>>((src),(dst),(R),(C))
  TP(enc_w1, enc_w1T, 512, 512);
  TP(enc_w2, enc_w2T, 512, 256);
  TP(post_w1 + (size_t)1024*1024, post_w1sT, 192, 1024);
  TP(post_w2, post_w2T, 1024, 2048);
  TP(amlp_w2, amlp_w2T, 512, 512);
  TP(gwih, WzT, 1024, 3072);
  TP(gwih + (size_t)1024*3072, WaT, 512, 3072);
  TP(gwhh, WhT, 1024, 3072);
  TP(lsd_w1, lsd_w1T, 1024, 1024);
  TP(lsd_w2, lsd_w2T, 1024, 2048);
  TP(dec_w1, dec_w1T, 2048, 1024);
  TP(dec_w2, dec_w2T, 1024, 512);
  TP(sd_w, sd_wT, 2048, 128);
  #undef TP

  k_cast<<<512,256,0,stream>>>(obs, obsb, 256*512);
  k_cast_state<<<64,256,0,stream>>>(state, PIN);
  k_acth1<<<32768,256,0,stream>>>(act, amlp_w1, amlp_b1, H1);

  hipMemsetAsync(Hbuf, 0, (size_t)256*1024*2, stream);

  k_gemm16<<<dim3(8,16),256,0,stream>>>(obsb, 512, enc_w1T, enc_b1, E1, 512, 0, 512, 1);
  k_gemm16<<<dim3(2,16),256,0,stream>>>(E1, 512, enc_w2T, enc_b2, PIN, 192, 64, 512, 0);
  k_gemm16<<<dim3(16,16),256,0,stream>>>(PIN, 192, post_w1sT, post_b1, P1, 1024, 0, 192, 1);
  k_gauss<<<dim3(16,16),256,0,stream>>>(P1, post_w2T, post_b2, eps0, Zbuf, 1024);
  k_aev2<<<dim3(4,128),256,0,stream>>>(H1, amlp_w2T, amlp_b2, AEb);

  // --- scan: cooperative if it provably fits, else verified per-step path ---
  int MB = 0;
  {
    int nb = 0;
    if (hipOccupancyMaxActiveBlocksPerMultiprocessor(&nb, k_scan, 256, 0) == hipSuccess){
      if (nb >= 4)      MB = 16;   // 1024 blocks, 4/CU
      else if (nb >= 2) MB = 8;    // 512 blocks, 2/CU
    }
  }
  if (MB){
    void* sa[] = { (void*)&Zbuf, (void*)&Hbuf, (void*)&AEb,
                   (void*)&WzT, (void*)&WhT, (void*)&WaT,
                   (void*)&gbih, (void*)&gbhh,
                   (void*)&lsd_w1T, (void*)&lsd_b1,
                   (void*)&lsd_w2T, (void*)&lsd_b2,
                   (void*)&epss, (void*)&X };
    if (hipLaunchCooperativeKernel((void*)k_scan, dim3(64*MB), dim3(256), sa, 0, stream)
        != hipSuccess)
      MB = 0;
  }
  if (!MB){
    for (int t=0; t<64; t++){
      const bf16* Zt = Zbuf + (size_t)t*262144;
      const bf16* Ht = Hbuf + (size_t)t*262144;
      bf16* Htn = Hbuf + (size_t)(t+1)*262144;
      bf16* Ztn = Zbuf + (size_t)(t+1)*262144;
      k_gru2<<<1024,256,0,stream>>>(Zt, Ht, AEb + (size_t)t*131072, WzT, WhT, WaT, gbih, gbhh, Htn);
      k_lsd1<<<1024,256,0,stream>>>(Htn, lsd_w1T, lsd_b1, X);
      k_lsd2<<<1024,256,0,stream>>>(X, lsd_w2T, lsd_b2, epss + (size_t)t*262144, Ztn);
    }
  }

  // --- decode ---
  k_dec1v2<<<dim3(8,128),256,0,stream>>>(Zbuf, Hbuf, dec_w1T, dec_b1, Y1);
  k_out1v2<<<dim3(4,128),256,0,stream>>>(Y1, dec_w2T, dec_b2, out);
  k_sd<<<512,256,0,stream>>>(Zbuf, Hbuf, sd_wT, sd_b, out);
}

// Round 4
// 4056.429 us; speedup vs baseline: 3.7280x; 3.7280x over previous
//
#include <hip/hip_runtime.h>
#include <hip/hip_bf16.h>

typedef __attribute__((ext_vector_type(8))) short short8;
typedef __attribute__((ext_vector_type(4))) float floatx4;
typedef __hip_bfloat16 bf16;

#define MFMA16(a,b,c) __builtin_amdgcn_mfma_f32_16x16x32_bf16((a),(b),(c),0,0,0)

__device__ __forceinline__ short8 ldf(const bf16* p){ return *(const short8*)p; }
__device__ __forceinline__ float fsig(float x){ return 1.f/(1.f+__expf(-x)); }
__device__ __forceinline__ float ftanh(float x){
  float c = fminf(fmaxf(x,-15.f),15.f);
  float e = __expf(2.f*c);
  return (e-1.f)/(e+1.f);
}

typedef __attribute__((address_space(1))) void gvoid;
typedef __attribute__((address_space(3))) void lvoid;
// async global->LDS, 16B per lane; LDS dest = uniform base + lane*16
__device__ __forceinline__ void stage16(const bf16* g, bf16* l){
  __builtin_amdgcn_global_load_lds((gvoid*)g, (lvoid*)l, 16, 0, 0);
}

// ---------------- fused weight prep: 13 transposes in ONE launch ----------------
// fp32 [R][C] -> bf16 [C][R], job table hardcoded (block counts = (C/32)*(R/32)).
struct TPJobs { const float* src[13]; bf16* dst[13]; };

__global__ __launch_bounds__(256) void k_transpose_all(TPJobs jobs){
  const int RR[13]  = {512,512,192,1024,512,1024,512,1024,1024,1024,2048,1024,2048};
  const int CCv[13] = {512,256,1024,2048,512,3072,3072,3072,1024,2048,1024,512,128};
  const int PFX[14] = {0,256,384,576,2624,2880,5952,7488,10560,11584,13632,15680,16192,16448};
  int b = blockIdx.x;
  int j = 0;
  #pragma unroll
  for (int i=0;i<13;i++) if (b >= PFX[i+1]) j = i+1;
  const int local = b - PFX[j];
  const int C = CCv[j], R = RR[j];
  const int cw = C >> 5;
  const int bx = local % cw, by = local / cw;
  const float* in = jobs.src[j];
  bf16* out = jobs.dst[j];
  __shared__ float t[32][33];
  int bc = bx*32, br = by*32;
  int tx = threadIdx.x & 31, ty = threadIdx.x >> 5;
  #pragma unroll
  for (int i=0;i<32;i+=8) t[ty+i][tx] = in[(size_t)(br+ty+i)*C + bc+tx];
  __syncthreads();
  #pragma unroll
  for (int i=0;i<32;i+=8) out[(size_t)(bc+ty+i)*R + br+tx] = __float2bfloat16(t[tx][ty+i]);
}

__global__ __launch_bounds__(256) void k_cast(const float* __restrict__ in, bf16* __restrict__ out, int n){
  int i = blockIdx.x*256+threadIdx.x;
  if (i<n) out[i] = __float2bfloat16(in[i]);
}

__global__ __launch_bounds__(256) void k_cast_state(const float* __restrict__ st, bf16* __restrict__ pin){
  int i = blockIdx.x*256+threadIdx.x; // 16384
  int r = i >> 6, c = i & 63;
  pin[r*192 + c] = __float2bfloat16(st[i]);
}

__global__ __launch_bounds__(256) void k_acth1(const float* __restrict__ act,
                                               const float* __restrict__ w1,
                                               const float* __restrict__ b1,
                                               bf16* __restrict__ H1){
  int idx = blockIdx.x*256 + threadIdx.x;
  int c = idx & 511; int r = idx >> 9;
  int t = r >> 8, b = r & 255;
  const float* a = act + (b*64 + t)*6;
  float s = b1[c];
  #pragma unroll
  for (int i=0;i<6;i++) s += a[i]*w1[i*512+c];
  H1[r*512+c] = __float2bfloat16(ftanh(s));
}

// ---------------- generic GEMM (setup path only, small shapes) ----------------
__global__ __launch_bounds__(256) void k_gemm16(
  const bf16* __restrict__ A, int sA,
  const bf16* __restrict__ Bt,
  const float* __restrict__ bias,
  bf16* __restrict__ out, int sO, int oO,
  int K, int mode)
{
  int lane = threadIdx.x & 63, wave = threadIdx.x >> 6;
  int lr = lane & 15, lq = lane >> 4;
  int j0 = blockIdx.x*64 + wave*16;
  int m0 = blockIdx.y*16;
  const bf16* Ap = A + (m0+lr)*sA + lq*8;
  const bf16* Bp = Bt + (j0+lr)*K + lq*8;
  floatx4 acc = {0.f,0.f,0.f,0.f};
  #pragma unroll 4
  for (int kb=0; kb<K; kb+=32){
    short8 a = ldf(Ap+kb);
    short8 b = ldf(Bp+kb);
    acc = MFMA16(a, b, acc);
  }
  #pragma unroll
  for (int i=0;i<4;i++){
    int m = m0 + lq*4 + i, j = j0 + lr;
    float v = acc[i] + bias[j];
    if (mode) v = ftanh(v);
    out[m*sO + oO + j] = __float2bfloat16(v);
  }
}

// ---------------- gaussian head (setup: z0) ----------------
__global__ __launch_bounds__(256) void k_gauss(
  const bf16* __restrict__ A, const bf16* __restrict__ Bt,
  const float* __restrict__ bias, const float* __restrict__ eps,
  bf16* __restrict__ out, int K)
{
  int lane = threadIdx.x & 63, wave = threadIdx.x >> 6;
  int lr = lane & 15, lq = lane >> 4;
  int j0 = blockIdx.x*64 + wave*16;
  int m0 = blockIdx.y*16;
  const bf16* Ap = A + (m0+lr)*K + lq*8;
  const bf16* Bm = Bt + (j0+lr)*K + lq*8;
  const bf16* Bl = Bt + (j0+1024+lr)*K + lq*8;
  floatx4 aM = {0.f,0.f,0.f,0.f}, aL = {0.f,0.f,0.f,0.f};
  #pragma unroll 4
  for (int kb=0;kb<K;kb+=32){
    short8 a = ldf(Ap+kb);
    aM = MFMA16(a, ldf(Bm+kb), aM);
    aL = MFMA16(a, ldf(Bl+kb), aL);
  }
  #pragma unroll
  for (int i=0;i<4;i++){
    int m = m0+lq*4+i, j = j0+lr;
    float z = aM[i] + bias[j] + __expf(aL[i] + bias[1024+j]) * eps[m*1024 + j];
    out[m*1024+j] = __float2bfloat16(z);
  }
}

// ---------------- AE gemm: 128x128 LDS tile ----------------
// AEb = H1 @ amlp_w2 + b2 : M=16384, N=512, K=512. grid (4,128). [verified r3]
__global__ __launch_bounds__(256) void k_aev2(
  const bf16* __restrict__ A, const bf16* __restrict__ W,
  const float* __restrict__ bias, bf16* __restrict__ Out)
{
  __shared__ __align__(16) bf16 As[128*32];
  __shared__ __align__(16) bf16 Bs[128*32];
  const int tid = threadIdx.x, lane = tid & 63, w = tid >> 6;
  const int lr = lane & 15, lq = lane >> 4;
  const int mh = (w & 1) * 64, jh = (w >> 1) * 64;
  const int m0 = blockIdx.y * 128, j0 = blockIdx.x * 128;
  const int cA0 = w*128 + lane,      cA1 = w*128 + 64 + lane;
  const int r0 = cA0>>2, o0 = (cA0&3)*8, r1 = cA1>>2, o1 = (cA1&3)*8;
  bf16* lA0 = As + (w*2+0)*512; bf16* lA1 = As + (w*2+1)*512;
  bf16* lB0 = Bs + (w*2+0)*512; bf16* lB1 = Bs + (w*2+1)*512;
  floatx4 acc[4][4] = {};
  for (int kb=0; kb<512; kb+=32){
    stage16(A + (size_t)(m0+r0)*512 + kb + o0, lA0);
    stage16(A + (size_t)(m0+r1)*512 + kb + o1, lA1);
    stage16(W + (size_t)(j0+r0)*512 + kb + o0, lB0);
    stage16(W + (size_t)(j0+r1)*512 + kb + o1, lB1);
    __syncthreads();
    short8 af[4], bfr[4];
    #pragma unroll
    for (int f=0; f<4; f++){
      af[f]  = *(const short8*)&As[(mh + f*16 + lr)*32 + lq*8];
      bfr[f] = *(const short8*)&Bs[(jh + f*16 + lr)*32 + lq*8];
    }
    #pragma unroll
    for (int mf=0; mf<4; mf++)
      #pragma unroll
      for (int jf=0; jf<4; jf++)
        acc[mf][jf] = MFMA16(af[mf], bfr[jf], acc[mf][jf]);
    __syncthreads();
  }
  #pragma unroll
  for (int mf=0; mf<4; mf++)
    #pragma unroll
    for (int jf=0; jf<4; jf++)
      #pragma unroll
      for (int i=0; i<4; i++){
        int m = m0 + mh + mf*16 + lq*4 + i;
        int j = j0 + jh + jf*16 + lr;
        Out[(size_t)m*512 + j] = __float2bfloat16(acc[mf][jf][i] + bias[j]);
      }
}

// ---------------- GI precompute: GI = AEb @ WaT + gate-bias, all 64 steps ----------------
// M=16384, N=3072, K=512, out bf16 stride 3072. grid (24,128).
// Bias fold: gates r,u (j<2048): bih[j]+bhh[j]; gate n (j>=2048): bih[j] only
// (bhh_n enters through r*(hn+bhh_n) in the GRU kernel).
__global__ __launch_bounds__(256) void k_giv2(
  const bf16* __restrict__ A, const bf16* __restrict__ W,
  const float* __restrict__ bih, const float* __restrict__ bhh,
  bf16* __restrict__ GI)
{
  __shared__ __align__(16) bf16 As[128*32];
  __shared__ __align__(16) bf16 Bs[128*32];
  const int tid = threadIdx.x, lane = tid & 63, w = tid >> 6;
  const int lr = lane & 15, lq = lane >> 4;
  const int mh = (w & 1) * 64, jh = (w >> 1) * 64;
  const int m0 = blockIdx.y * 128, j0 = blockIdx.x * 128;
  const int cA0 = w*128 + lane,      cA1 = w*128 + 64 + lane;
  const int r0 = cA0>>2, o0 = (cA0&3)*8, r1 = cA1>>2, o1 = (cA1&3)*8;
  bf16* lA0 = As + (w*2+0)*512; bf16* lA1 = As + (w*2+1)*512;
  bf16* lB0 = Bs + (w*2+0)*512; bf16* lB1 = Bs + (w*2+1)*512;
  floatx4 acc[4][4] = {};
  for (int kb=0; kb<512; kb+=32){
    stage16(A + (size_t)(m0+r0)*512 + kb + o0, lA0);
    stage16(A + (size_t)(m0+r1)*512 + kb + o1, lA1);
    stage16(W + (size_t)(j0+r0)*512 + kb + o0, lB0);
    stage16(W + (size_t)(j0+r1)*512 + kb + o1, lB1);
    __syncthreads();
    short8 af[4], bfr[4];
    #pragma unroll
    for (int f=0; f<4; f++){
      af[f]  = *(const short8*)&As[(mh + f*16 + lr)*32 + lq*8];
      bfr[f] = *(const short8*)&Bs[(jh + f*16 + lr)*32 + lq*8];
    }
    #pragma unroll
    for (int mf=0; mf<4; mf++)
      #pragma unroll
      for (int jf=0; jf<4; jf++)
        acc[mf][jf] = MFMA16(af[mf], bfr[jf], acc[mf][jf]);
    __syncthreads();
  }
  #pragma unroll
  for (int mf=0; mf<4; mf++)
    #pragma unroll
    for (int jf=0; jf<4; jf++)
      #pragma unroll
      for (int i=0; i<4; i++){
        int m = m0 + mh + mf*16 + lq*4 + i;
        int j = j0 + jh + jf*16 + lr;
        float bias = (j < 2048) ? (bih[j] + bhh[j]) : bih[j];
        GI[(size_t)m*3072 + j] = __float2bfloat16(acc[mf][jf][i] + bias);
      }
}

// ---------------- scan step kernels ----------------
// k_gru3: GI-based GRU. K=2048 (Z seg 1024 + H seg 1024), 4 waves each own an
// aligned 512-K slice: w0/w1 -> Z halves (R,U,NX), w2/w3 -> H halves (R,U,NH).
__global__ __launch_bounds__(256) void k_gru3(
  const bf16* __restrict__ Z, const bf16* __restrict__ H,
  const bf16* __restrict__ GI,
  const bf16* __restrict__ WzT, const bf16* __restrict__ WhT,
  const float* __restrict__ bhh,
  bf16* __restrict__ Hn)
{
  __shared__ float red[4][3][64][4];
  const int tid = threadIdx.x, lane = tid & 63, w = tid >> 6;
  const int lr = lane & 15, lq = lane >> 4;
  const int j0 = (blockIdx.x & 63) * 16, m0 = (blockIdx.x >> 6) * 16;
  const int jl = j0 + lr;
  floatx4 A0={},A1={},A2={};     // R, U, (NX for w<2 | NH for w>=2)
  {
    const int kbase = (w & 1) * 512;
    const bf16* Ap = (w < 2 ? Z : H) + (size_t)(m0+lr)*1024 + kbase + lq*8;
    const bf16* Wt = (w < 2 ? WzT : WhT);
    const bf16* B0 = Wt + (size_t)jl*1024        + kbase + lq*8;
    const bf16* B1p= Wt + (size_t)(jl+1024)*1024 + kbase + lq*8;
    const bf16* B2p= Wt + (size_t)(jl+2048)*1024 + kbase + lq*8;
    #pragma unroll 4
    for (int k=0; k<512; k+=32){
      short8 a = ldf(Ap+k);
      A0 = MFMA16(a, ldf(B0+k),  A0);
      A1 = MFMA16(a, ldf(B1p+k), A1);
      A2 = MFMA16(a, ldf(B2p+k), A2);
    }
  }
  *(floatx4*)&red[w][0][lane][0]=A0;
  *(floatx4*)&red[w][1][lane][0]=A1;
  *(floatx4*)&red[w][2][lane][0]=A2;
  __syncthreads();
  if (w==0){
    floatx4 sR={},sU={};
    #pragma unroll
    for (int ww=0;ww<4;ww++){
      sR += *(const floatx4*)&red[ww][0][lane][0];
      sU += *(const floatx4*)&red[ww][1][lane][0];
    }
    floatx4 sNX = *(const floatx4*)&red[0][2][lane][0];
    sNX        += *(const floatx4*)&red[1][2][lane][0];
    floatx4 sNH = *(const floatx4*)&red[2][2][lane][0];
    sNH        += *(const floatx4*)&red[3][2][lane][0];
    float bH = bhh[2048+jl];
    #pragma unroll
    for (int i=0;i<4;i++){
      int m = m0 + lq*4 + i;
      float gir = __bfloat162float(GI[(size_t)m*3072 + jl]);
      float giu = __bfloat162float(GI[(size_t)m*3072 + 1024 + jl]);
      float gin = __bfloat162float(GI[(size_t)m*3072 + 2048 + jl]);
      float r = fsig(sR[i] + gir);
      float u = fsig(sU[i] + giu);
      float n = ftanh(sNX[i] + gin + r*(sNH[i] + bH));
      float h = __bfloat162float(H[m*1024+jl]);
      Hn[m*1024+jl] = __float2bfloat16((1.f-u)*n + u*h);
    }
  }
}

// k_gru2: verified AE-segment fallback (used only if workspace can't hold GI)
__global__ __launch_bounds__(256) void k_gru2(
  const bf16* __restrict__ Z, const bf16* __restrict__ H, const bf16* __restrict__ AE,
  const bf16* __restrict__ WzT, const bf16* __restrict__ WhT, const bf16* __restrict__ WaT,
  const float* __restrict__ bih, const float* __restrict__ bhh,
  bf16* __restrict__ Hn)
{
  __shared__ float red[4][4][64][4];
  const int tid = threadIdx.x, lane = tid & 63, w = tid >> 6;
  const int lr = lane & 15, lq = lane >> 4;
  const int j0 = (blockIdx.x & 63) * 16, m0 = (blockIdx.x >> 6) * 16;
  const int jl = j0 + lr;
  const int c0 = w*640, c1 = c0+640;
  floatx4 R={},U={},NX={},NH={};
  {
    int hi = c1 < 1024 ? c1 : 1024;
    for (int k=c0; k<hi; k+=32){
      short8 a = ldf(Z + (m0+lr)*1024 + k + lq*8);
      const bf16* bp = WzT + k + lq*8;
      R = MFMA16(a, ldf(bp + (size_t)jl*1024), R);
      U = MFMA16(a, ldf(bp + (size_t)(jl+1024)*1024), U);
      NX= MFMA16(a, ldf(bp + (size_t)(jl+2048)*1024), NX);
    }
  }
  {
    int lo = c0 > 1024 ? c0 : 1024;
    int hi = c1 < 1536 ? c1 : 1536;
    for (int k=lo; k<hi; k+=32){
      int kk = k - 1024;
      short8 a = ldf(AE + (m0+lr)*512 + kk + lq*8);
      const bf16* bp = WaT + kk + lq*8;
      R = MFMA16(a, ldf(bp + (size_t)jl*512), R);
      U = MFMA16(a, ldf(bp + (size_t)(jl+1024)*512), U);
      NX= MFMA16(a, ldf(bp + (size_t)(jl+2048)*512), NX);
    }
  }
  {
    int lo = c0 > 1536 ? c0 : 1536;
    for (int k=lo; k<c1; k+=32){
      int kk = k - 1536;
      short8 a = ldf(H + (m0+lr)*1024 + kk + lq*8);
      const bf16* bp = WhT + kk + lq*8;
      R = MFMA16(a, ldf(bp + (size_t)jl*1024), R);
      U = MFMA16(a, ldf(bp + (size_t)(jl+1024)*1024), U);
      NH= MFMA16(a, ldf(bp + (size_t)(jl+2048)*1024), NH);
    }
  }
  *(floatx4*)&red[w][0][lane][0]=R;
  *(floatx4*)&red[w][1][lane][0]=U;
  *(floatx4*)&red[w][2][lane][0]=NX;
  *(floatx4*)&red[w][3][lane][0]=NH;
  __syncthreads();
  if (w==0){
    floatx4 sR={},sU={},sNX={},sNH={};
    #pragma unroll
    for (int ww=0;ww<4;ww++){
      sR += *(const floatx4*)&red[ww][0][lane][0];
      sU += *(const floatx4*)&red[ww][1][lane][0];
      sNX+= *(const floatx4*)&red[ww][2][lane][0];
      sNH+= *(const floatx4*)&red[ww][3][lane][0];
    }
    float bR = bih[jl]+bhh[jl];
    float bU = bih[1024+jl]+bhh[1024+jl];
    float bX = bih[2048+jl], bH = bhh[2048+jl];
    #pragma unroll
    for (int i=0;i<4;i++){
      int m = m0 + lq*4 + i;
      float r = fsig(sR[i]+bR);
      float u = fsig(sU[i]+bU);
      float n = ftanh(sNX[i]+bX + r*(sNH[i]+bH));
      float h = __bfloat162float(H[m*1024+jl]);
      Hn[m*1024+jl] = __float2bfloat16((1.f-u)*n + u*h);
    }
  }
}

__global__ __launch_bounds__(256) void k_lsd1(
  const bf16* __restrict__ Hn, const bf16* __restrict__ Lw1,
  const float* __restrict__ Lb1, bf16* __restrict__ X)
{
  __shared__ float red[4][64][4];
  const int tid = threadIdx.x, lane = tid & 63, w = tid >> 6;
  const int lr = lane & 15, lq = lane >> 4;
  const int j0 = (blockIdx.x & 63) * 16, m0 = (blockIdx.x >> 6) * 16;
  const int jl = j0 + lr;
  floatx4 C={};
  const bf16* Ap = Hn + (m0+lr)*1024 + lq*8;
  const bf16* Bp = Lw1 + (size_t)jl*1024 + lq*8;
  #pragma unroll
  for (int k=w*256; k<w*256+256; k+=32)
    C = MFMA16(ldf(Ap+k), ldf(Bp+k), C);
  *(floatx4*)&red[w][lane][0] = C;
  __syncthreads();
  if (w==0){
    floatx4 s={};
    #pragma unroll
    for (int ww=0;ww<4;ww++) s += *(const floatx4*)&red[ww][lane][0];
    float bb = Lb1[jl];
    #pragma unroll
    for (int i=0;i<4;i++){
      int m = m0 + lq*4 + i;
      X[m*1024+jl] = __float2bfloat16(ftanh(s[i]+bb));
    }
  }
}

__global__ __launch_bounds__(256) void k_lsd2(
  const bf16* __restrict__ X, const bf16* __restrict__ Lw2,
  const float* __restrict__ Lb2, const float* __restrict__ eps,
  bf16* __restrict__ Zn)
{
  __shared__ float red[4][2][64][4];
  const int tid = threadIdx.x, lane = tid & 63, w = tid >> 6;
  const int lr = lane & 15, lq = lane >> 4;
  const int j0 = (blockIdx.x & 63) * 16, m0 = (blockIdx.x >> 6) * 16;
  const int jl = j0 + lr;
  floatx4 M={}, L={};
  const bf16* Ap = X + (m0+lr)*1024 + lq*8;
  const bf16* Bm = Lw2 + (size_t)jl*1024 + lq*8;
  const bf16* Bl = Lw2 + (size_t)(1024+jl)*1024 + lq*8;
  #pragma unroll
  for (int k=w*256; k<w*256+256; k+=32){
    short8 a = ldf(Ap+k);
    M = MFMA16(a, ldf(Bm+k), M);
    L = MFMA16(a, ldf(Bl+k), L);
  }
  *(floatx4*)&red[w][0][lane][0] = M;
  *(floatx4*)&red[w][1][lane][0] = L;
  __syncthreads();
  if (w==0){
    floatx4 sM={}, sL={};
    #pragma unroll
    for (int ww=0;ww<4;ww++){
      sM += *(const floatx4*)&red[ww][0][lane][0];
      sL += *(const floatx4*)&red[ww][1][lane][0];
    }
    float bmu = Lb2[jl], bls = Lb2[1024+jl];
    #pragma unroll
    for (int i=0;i<4;i++){
      int m = m0 + lq*4 + i;
      float z = sM[i]+bmu + __expf(sL[i]+bls) * eps[m*1024+jl];
      Zn[m*1024+jl] = __float2bfloat16(z);
    }
  }
}

// ---------------- decode: 128x128 LDS-tiled GEMM with global_load_lds ----------------
__global__ __launch_bounds__(256) void k_dec1v2(
  const bf16* __restrict__ Zb, const bf16* __restrict__ Hb,
  const bf16* __restrict__ W, const float* __restrict__ bias,
  bf16* __restrict__ Y)
{
  __shared__ __align__(16) bf16 As[128*32];
  __shared__ __align__(16) bf16 Bs[128*32];
  const int tid = threadIdx.x, lane = tid & 63, w = tid >> 6;
  const int lr = lane & 15, lq = lane >> 4;
  const int mh = (w & 1) * 64, jh = (w >> 1) * 64;
  const int m0 = blockIdx.y * 128, j0 = blockIdx.x * 128;
  const int cA0 = w*128 + lane,      cA1 = w*128 + 64 + lane;
  const int r0 = cA0>>2, o0 = (cA0&3)*8, r1 = cA1>>2, o1 = (cA1&3)*8;
  bf16* lA0 = As + (w*2+0)*512; bf16* lA1 = As + (w*2+1)*512;
  bf16* lB0 = Bs + (w*2+0)*512; bf16* lB1 = Bs + (w*2+1)*512;
  floatx4 acc[4][4] = {};
  const bf16* Aseg[2] = { Zb + 256*1024, Hb + 256*1024 };
  #pragma unroll
  for (int seg=0; seg<2; seg++){
    const bf16* A = Aseg[seg];
    const bf16* Wb = W + seg*1024;
    for (int kb=0; kb<1024; kb+=32){
      stage16(A  + (size_t)(m0+r0)*1024 + kb + o0, lA0);
      stage16(A  + (size_t)(m0+r1)*1024 + kb + o1, lA1);
      stage16(Wb + (size_t)(j0+r0)*2048 + kb + o0, lB0);
      stage16(Wb + (size_t)(j0+r1)*2048 + kb + o1, lB1);
      __syncthreads();
      short8 af[4], bfr[4];
      #pragma unroll
      for (int f=0; f<4; f++){
        af[f]  = *(const short8*)&As[(mh + f*16 + lr)*32 + lq*8];
        bfr[f] = *(const short8*)&Bs[(jh + f*16 + lr)*32 + lq*8];
      }
      #pragma unroll
      for (int mf=0; mf<4; mf++)
        #pragma unroll
        for (int jf=0; jf<4; jf++)
          acc[mf][jf] = MFMA16(af[mf], bfr[jf], acc[mf][jf]);
      __syncthreads();
    }
  }
  #pragma unroll
  for (int mf=0; mf<4; mf++)
    #pragma unroll
    for (int jf=0; jf<4; jf++)
      #pragma unroll
      for (int i=0; i<4; i++){
        int m = m0 + mh + mf*16 + lq*4 + i;
        int j = j0 + jh + jf*16 + lr;
        Y[(size_t)m*1024 + j] = __float2bfloat16(ftanh(acc[mf][jf][i] + bias[j]));
      }
}

__global__ __launch_bounds__(256) void k_out1v2(
  const bf16* __restrict__ Yb, const bf16* __restrict__ W,
  const float* __restrict__ bias, float* __restrict__ out)
{
  __shared__ __align__(16) bf16 As[128*32];
  __shared__ __align__(16) bf16 Bs[128*32];
  const int tid = threadIdx.x, lane = tid & 63, w = tid >> 6;
  const int lr = lane & 15, lq = lane >> 4;
  const int mh = (w & 1) * 64, jh = (w >> 1) * 64;
  const int m0 = blockIdx.y * 128, j0 = blockIdx.x * 128;
  const int cA0 = w*128 + lane,      cA1 = w*128 + 64 + lane;
  const int r0 = cA0>>2, o0 = (cA0&3)*8, r1 = cA1>>2, o1 = (cA1&3)*8;
  bf16* lA0 = As + (w*2+0)*512; bf16* lA1 = As + (w*2+1)*512;
  bf16* lB0 = Bs + (w*2+0)*512; bf16* lB1 = Bs + (w*2+1)*512;
  floatx4 acc[4][4] = {};
  for (int kb=0; kb<1024; kb+=32){
    stage16(Yb + (size_t)(m0+r0)*1024 + kb + o0, lA0);
    stage16(Yb + (size_t)(m0+r1)*1024 + kb + o1, lA1);
    stage16(W  + (size_t)(j0+r0)*1024 + kb + o0, lB0);
    stage16(W  + (size_t)(j0+r1)*1024 + kb + o1, lB1);
    __syncthreads();
    short8 af[4], bfr[4];
    #pragma unroll
    for (int f=0; f<4; f++){
      af[f]  = *(const short8*)&As[(mh + f*16 + lr)*32 + lq*8];
      bfr[f] = *(const short8*)&Bs[(jh + f*16 + lr)*32 + lq*8];
    }
    #pragma unroll
    for (int mf=0; mf<4; mf++)
      #pragma unroll
      for (int jf=0; jf<4; jf++)
        acc[mf][jf] = MFMA16(af[mf], bfr[jf], acc[mf][jf]);
    __syncthreads();
  }
  #pragma unroll
  for (int mf=0; mf<4; mf++)
    #pragma unroll
    for (int jf=0; jf<4; jf++)
      #pragma unroll
      for (int i=0; i<4; i++){
        int m = m0 + mh + mf*16 + lq*4 + i;
        int j = j0 + jh + jf*16 + lr;
        int b = m & 255, t = m >> 8;
        out[(size_t)b*40960 + t*640 + j] = acc[mf][jf][i] + bias[j];
      }
}

__global__ __launch_bounds__(256) void k_sd(
  const bf16* __restrict__ Zb, const bf16* __restrict__ Hb,
  const bf16* __restrict__ W, const float* __restrict__ bias,
  float* __restrict__ out)
{
  int lane = threadIdx.x & 63, wave = threadIdx.x >> 6;
  int lr = lane & 15, lq = lane >> 4;
  int m0 = blockIdx.x * 32;
  int j0 = wave * 16;
  floatx4 aM[2] = {}, aL[2] = {};
  const bf16* Az = Zb + 256*1024;
  const bf16* Ah = Hb + 256*1024;
  #pragma unroll 2
  for (int kb=0; kb<1024; kb+=32){
    short8 a0 = ldf(Az + (m0+lr)*1024 + kb + lq*8);
    short8 a1 = ldf(Az + (m0+16+lr)*1024 + kb + lq*8);
    short8 bm = ldf(W + (size_t)(j0+lr)*2048 + kb + lq*8);
    short8 bl = ldf(W + (size_t)(j0+64+lr)*2048 + kb + lq*8);
    aM[0] = MFMA16(a0,bm,aM[0]); aM[1] = MFMA16(a1,bm,aM[1]);
    aL[0] = MFMA16(a0,bl,aL[0]); aL[1] = MFMA16(a1,bl,aL[1]);
  }
  #pragma unroll 2
  for (int kb=0; kb<1024; kb+=32){
    short8 a0 = ldf(Ah + (m0+lr)*1024 + kb + lq*8);
    short8 a1 = ldf(Ah + (m0+16+lr)*1024 + kb + lq*8);
    short8 bm = ldf(W + (size_t)(j0+lr)*2048 + 1024 + kb + lq*8);
    short8 bl = ldf(W + (size_t)(j0+64+lr)*2048 + 1024 + kb + lq*8);
    aM[0] = MFMA16(a0,bm,aM[0]); aM[1] = MFMA16(a1,bm,aM[1]);
    aL[0] = MFMA16(a0,bl,aL[0]); aL[1] = MFMA16(a1,bl,aL[1]);
  }
  #pragma unroll
  for (int rf=0;rf<2;rf++)
    #pragma unroll
    for (int i=0;i<4;i++){
      int m = m0 + rf*16 + lq*4 + i;
      int j = j0 + lr;
      int b = m & 255, t = m >> 8;
      out[b*40960 + t*640 + 512 + j] = aM[rf][i] + bias[j];
      out[b*40960 + t*640 + 576 + j] = __expf(aL[rf][i] + bias[64+j]);
    }
}

extern "C" void kernel_launch(void* const* d_in, const int* in_sizes, int n_in,
                              void* d_out, int out_size, void* d_ws, size_t ws_size,
                              hipStream_t stream)
{
  const float* obs    = (const float*)d_in[0];
  const float* state  = (const float*)d_in[1];
  const float* act    = (const float*)d_in[2];
  const float* eps0   = (const float*)d_in[3];
  const float* epss   = (const float*)d_in[4];
  const float* enc_w1 = (const float*)d_in[5];  const float* enc_b1 = (const float*)d_in[6];
  const float* enc_w2 = (const float*)d_in[7];  const float* enc_b2 = (const float*)d_in[8];
  const float* post_w1= (const float*)d_in[9];  const float* post_b1= (const float*)d_in[10];
  const float* post_w2= (const float*)d_in[11]; const float* post_b2= (const float*)d_in[12];
  const float* amlp_w1= (const float*)d_in[13]; const float* amlp_b1= (const float*)d_in[14];
  const float* amlp_w2= (const float*)d_in[15]; const float* amlp_b2= (const float*)d_in[16];
  const float* gwih   = (const float*)d_in[17];
  const float* gwhh   = (const float*)d_in[18];
  const float* gbih   = (const float*)d_in[19];
  const float* gbhh   = (const float*)d_in[20];
  const float* lsd_w1 = (const float*)d_in[21]; const float* lsd_b1 = (const float*)d_in[22];
  const float* lsd_w2 = (const float*)d_in[23]; const float* lsd_b2 = (const float*)d_in[24];
  const float* dec_w1 = (const float*)d_in[25]; const float* dec_b1 = (const float*)d_in[26];
  const float* dec_w2 = (const float*)d_in[27]; const float* dec_b2 = (const float*)d_in[28];
  const float* sd_w   = (const float*)d_in[29]; const float* sd_b   = (const float*)d_in[30];
  float* out = (float*)d_out;

  char* w = (char*)d_ws;
  size_t off = 0;
  auto alloc = [&](size_t elems)->bf16* {
    bf16* p = (bf16*)(w + off);
    off += ((elems*2 + 255)/256)*256;
    return p;
  };
  bf16* WzT      = alloc((size_t)3072*1024);
  bf16* WhT      = alloc((size_t)3072*1024);
  bf16* WaT      = alloc((size_t)3072*512);
  bf16* lsd_w1T  = alloc((size_t)1024*1024);
  bf16* lsd_w2T  = alloc((size_t)2048*1024);
  bf16* dec_w1T  = alloc((size_t)1024*2048);
  bf16* dec_w2T  = alloc((size_t)512*1024);
  bf16* sd_wT    = alloc((size_t)128*2048);
  bf16* enc_w1T  = alloc((size_t)512*512);
  bf16* enc_w2T  = alloc((size_t)256*512);
  bf16* post_w1sT= alloc((size_t)1024*192);
  bf16* post_w2T = alloc((size_t)2048*1024);
  bf16* amlp_w2T = alloc((size_t)512*512);
  bf16* obsb     = alloc((size_t)256*512);
  bf16* E1       = alloc((size_t)256*512);
  bf16* PIN      = alloc((size_t)256*192);
  bf16* P1       = alloc((size_t)256*1024);
  bf16* X        = alloc((size_t)256*1024);
  bf16* Zbuf     = alloc((size_t)65*256*1024);
  bf16* Hbuf     = alloc((size_t)65*256*1024);
  bf16* AEb      = alloc((size_t)16384*512);
  size_t off_noGI = off + (((size_t)16384*1024*2 + 255)/256)*256; // old high-water (Y1 only)
  bf16* R        = alloc((size_t)16384*3072);   // union region: H1 / GI / Y1
  bf16* Y1       = R;
  bf16* GI       = R;
  bf16* H1       = R;      // H1 dead before GI written; GI dead before Y1 written
  const bool useGI = (ws_size >= off);
  (void)off_noGI;

  // --- weight prep: ONE fused transpose launch ---
  TPJobs jobs;
  jobs.src[0]=enc_w1;  jobs.dst[0]=enc_w1T;
  jobs.src[1]=enc_w2;  jobs.dst[1]=enc_w2T;
  jobs.src[2]=post_w1 + (size_t)1024*1024; jobs.dst[2]=post_w1sT;
  jobs.src[3]=post_w2; jobs.dst[3]=post_w2T;
  jobs.src[4]=amlp_w2; jobs.dst[4]=amlp_w2T;
  jobs.src[5]=gwih;    jobs.dst[5]=WzT;
  jobs.src[6]=gwih + (size_t)1024*3072; jobs.dst[6]=WaT;
  jobs.src[7]=gwhh;    jobs.dst[7]=WhT;
  jobs.src[8]=lsd_w1;  jobs.dst[8]=lsd_w1T;
  jobs.src[9]=lsd_w2;  jobs.dst[9]=lsd_w2T;
  jobs.src[10]=dec_w1; jobs.dst[10]=dec_w1T;
  jobs.src[11]=dec_w2; jobs.dst[11]=dec_w2T;
  jobs.src[12]=sd_w;   jobs.dst[12]=sd_wT;
  k_transpose_all<<<16448,256,0,stream>>>(jobs);

  k_cast<<<512,256,0,stream>>>(obs, obsb, 256*512);
  k_cast_state<<<64,256,0,stream>>>(state, PIN);
  k_acth1<<<32768,256,0,stream>>>(act, amlp_w1, amlp_b1, H1);

  hipMemsetAsync(Hbuf, 0, (size_t)256*1024*2, stream);

  k_gemm16<<<dim3(8,16),256,0,stream>>>(obsb, 512, enc_w1T, enc_b1, E1, 512, 0, 512, 1);
  k_gemm16<<<dim3(2,16),256,0,stream>>>(E1, 512, enc_w2T, enc_b2, PIN, 192, 64, 512, 0);
  k_gemm16<<<dim3(16,16),256,0,stream>>>(PIN, 192, post_w1sT, post_b1, P1, 1024, 0, 192, 1);
  k_gauss<<<dim3(16,16),256,0,stream>>>(P1, post_w2T, post_b2, eps0, Zbuf, 1024);
  k_aev2<<<dim3(4,128),256,0,stream>>>(H1, amlp_w2T, amlp_b2, AEb);
  if (useGI)
    k_giv2<<<dim3(24,128),256,0,stream>>>(AEb, WaT, gbih, gbhh, GI);  // overwrites H1 (dead)

  // --- sequential scan: 3 kernels per step, launches are the sync mechanism ---
  for (int t=0; t<64; t++){
    const bf16* Zt = Zbuf + (size_t)t*262144;
    const bf16* Ht = Hbuf + (size_t)t*262144;
    bf16* Htn = Hbuf + (size_t)(t+1)*262144;
    bf16* Ztn = Zbuf + (size_t)(t+1)*262144;
    if (useGI)
      k_gru3<<<1024,256,0,stream>>>(Zt, Ht, GI + (size_t)t*256*3072, WzT, WhT, gbhh, Htn);
    else
      k_gru2<<<1024,256,0,stream>>>(Zt, Ht, AEb + (size_t)t*131072, WzT, WhT, WaT, gbih, gbhh, Htn);
    k_lsd1<<<1024,256,0,stream>>>(Htn, lsd_w1T, lsd_b1, X);
    k_lsd2<<<1024,256,0,stream>>>(X, lsd_w2T, lsd_b2, epss + (size_t)t*262144, Ztn);
  }

  // --- decode (Y1 overwrites GI region — GI dead after scan) ---
  k_dec1v2<<<dim3(8,128),256,0,stream>>>(Zbuf, Hbuf, dec_w1T, dec_b1, Y1);
  k_out1v2<<<dim3(4,128),256,0,stream>>>(Y1, dec_w2T, dec_b2, out);
  k_sd<<<512,256,0,stream>>>(Zbuf, Hbuf, sd_wT, sd_b, out);
}

// Round 5
// 4004.081 us; speedup vs baseline: 3.7767x; 1.0131x over previous
//
#include <hip/hip_runtime.h>
#include <hip/hip_bf16.h>

typedef __attribute__((ext_vector_type(8))) short short8;
typedef __attribute__((ext_vector_type(4))) float floatx4;
typedef __hip_bfloat16 bf16;

#define MFMA16(a,b,c) __builtin_amdgcn_mfma_f32_16x16x32_bf16((a),(b),(c),0,0,0)

__device__ __forceinline__ short8 ldf(const bf16* p){ return *(const short8*)p; }
__device__ __forceinline__ float fsig(float x){ return 1.f/(1.f+__expf(-x)); }
__device__ __forceinline__ float ftanh(float x){
  float c = fminf(fmaxf(x,-15.f),15.f);
  float e = __expf(2.f*c);
  return (e-1.f)/(e+1.f);
}

typedef __attribute__((address_space(1))) void gvoid;
typedef __attribute__((address_space(3))) void lvoid;
// async global->LDS, 16B per lane; LDS dest = uniform base + lane*16
__device__ __forceinline__ void stage16(const bf16* g, bf16* l){
  __builtin_amdgcn_global_load_lds((gvoid*)g, (lvoid*)l, 16, 0, 0);
}

// LDS tile layout [128 rows][32 bf16], row stride 64B. Unswizzled, a 16-lane
// quarter-wave reads 16 rows at fixed 16B chunk -> banks (row*16)%32 = 2 banks
// = 8-way conflict (8.39M conflict cycles measured on k_dec1v2, r4). Swizzle:
// chunk' = chunk ^ ((row>>1)&3). Applied on BOTH the global-source side of
// global_load_lds (LDS dest must stay linear, rule #21) and the read address.
// After: 16 lanes spread over 8 banks = 2-way = free (m136).
__device__ __forceinline__ int swz_src_off(int c){            // element offset in row
  return (((c & 3) ^ ((c >> 3) & 3)) << 3);
}
__device__ __forceinline__ int swz_rd(int row, int lq){       // element offset in tile
  return row*32 + (((lq ^ (row >> 1)) & 3) << 3);
}

// ---------------- fused weight prep: 13 transposes in ONE launch ----------------
struct TPJobs { const float* src[13]; bf16* dst[13]; };

__global__ __launch_bounds__(256) void k_transpose_all(TPJobs jobs){
  const int RR[13]  = {512,512,192,1024,512,1024,512,1024,1024,1024,2048,1024,2048};
  const int CCv[13] = {512,256,1024,2048,512,3072,3072,3072,1024,2048,1024,512,128};
  const int PFX[14] = {0,256,384,576,2624,2880,5952,7488,10560,11584,13632,15680,16192,16448};
  int b = blockIdx.x;
  int j = 0;
  #pragma unroll
  for (int i=0;i<13;i++) if (b >= PFX[i+1]) j = i+1;
  const int local = b - PFX[j];
  const int C = CCv[j], R = RR[j];
  const int cw = C >> 5;
  const int bx = local % cw, by = local / cw;
  const float* in = jobs.src[j];
  bf16* out = jobs.dst[j];
  __shared__ float t[32][33];
  int bc = bx*32, br = by*32;
  int tx = threadIdx.x & 31, ty = threadIdx.x >> 5;
  #pragma unroll
  for (int i=0;i<32;i+=8) t[ty+i][tx] = in[(size_t)(br+ty+i)*C + bc+tx];
  __syncthreads();
  #pragma unroll
  for (int i=0;i<32;i+=8) out[(size_t)(bc+ty+i)*R + br+tx] = __float2bfloat16(t[tx][ty+i]);
}

__global__ __launch_bounds__(256) void k_cast(const float* __restrict__ in, bf16* __restrict__ out, int n){
  int i = blockIdx.x*256+threadIdx.x;
  if (i<n) out[i] = __float2bfloat16(in[i]);
}

__global__ __launch_bounds__(256) void k_cast_state(const float* __restrict__ st, bf16* __restrict__ pin){
  int i = blockIdx.x*256+threadIdx.x; // 16384
  int r = i >> 6, c = i & 63;
  pin[r*192 + c] = __float2bfloat16(st[i]);
}

__global__ __launch_bounds__(256) void k_acth1(const float* __restrict__ act,
                                               const float* __restrict__ w1,
                                               const float* __restrict__ b1,
                                               bf16* __restrict__ H1){
  int idx = blockIdx.x*256 + threadIdx.x;
  int c = idx & 511; int r = idx >> 9;
  int t = r >> 8, b = r & 255;
  const float* a = act + (b*64 + t)*6;
  float s = b1[c];
  #pragma unroll
  for (int i=0;i<6;i++) s += a[i]*w1[i*512+c];
  H1[r*512+c] = __float2bfloat16(ftanh(s));
}

// ---------------- generic GEMM (setup path only, small shapes) ----------------
__global__ __launch_bounds__(256) void k_gemm16(
  const bf16* __restrict__ A, int sA,
  const bf16* __restrict__ Bt,
  const float* __restrict__ bias,
  bf16* __restrict__ out, int sO, int oO,
  int K, int mode)
{
  int lane = threadIdx.x & 63, wave = threadIdx.x >> 6;
  int lr = lane & 15, lq = lane >> 4;
  int j0 = blockIdx.x*64 + wave*16;
  int m0 = blockIdx.y*16;
  const bf16* Ap = A + (m0+lr)*sA + lq*8;
  const bf16* Bp = Bt + (j0+lr)*K + lq*8;
  floatx4 acc = {0.f,0.f,0.f,0.f};
  #pragma unroll 4
  for (int kb=0; kb<K; kb+=32){
    short8 a = ldf(Ap+kb);
    short8 b = ldf(Bp+kb);
    acc = MFMA16(a, b, acc);
  }
  #pragma unroll
  for (int i=0;i<4;i++){
    int m = m0 + lq*4 + i, j = j0 + lr;
    float v = acc[i] + bias[j];
    if (mode) v = ftanh(v);
    out[m*sO + oO + j] = __float2bfloat16(v);
  }
}

// ---------------- gaussian head (setup: z0) ----------------
__global__ __launch_bounds__(256) void k_gauss(
  const bf16* __restrict__ A, const bf16* __restrict__ Bt,
  const float* __restrict__ bias, const float* __restrict__ eps,
  bf16* __restrict__ out, int K)
{
  int lane = threadIdx.x & 63, wave = threadIdx.x >> 6;
  int lr = lane & 15, lq = lane >> 4;
  int j0 = blockIdx.x*64 + wave*16;
  int m0 = blockIdx.y*16;
  const bf16* Ap = A + (m0+lr)*K + lq*8;
  const bf16* Bm = Bt + (j0+lr)*K + lq*8;
  const bf16* Bl = Bt + (j0+1024+lr)*K + lq*8;
  floatx4 aM = {0.f,0.f,0.f,0.f}, aL = {0.f,0.f,0.f,0.f};
  #pragma unroll 4
  for (int kb=0;kb<K;kb+=32){
    short8 a = ldf(Ap+kb);
    aM = MFMA16(a, ldf(Bm+kb), aM);
    aL = MFMA16(a, ldf(Bl+kb), aL);
  }
  #pragma unroll
  for (int i=0;i<4;i++){
    int m = m0+lq*4+i, j = j0+lr;
    float z = aM[i] + bias[j] + __expf(aL[i] + bias[1024+j]) * eps[m*1024 + j];
    out[m*1024+j] = __float2bfloat16(z);
  }
}

// ---------------- AE gemm: 128x128 LDS tile, swizzled ----------------
__global__ __launch_bounds__(256) void k_aev2(
  const bf16* __restrict__ A, const bf16* __restrict__ W,
  const float* __restrict__ bias, bf16* __restrict__ Out)
{
  __shared__ __align__(16) bf16 As[128*32];
  __shared__ __align__(16) bf16 Bs[128*32];
  const int tid = threadIdx.x, lane = tid & 63, w = tid >> 6;
  const int lr = lane & 15, lq = lane >> 4;
  const int mh = (w & 1) * 64, jh = (w >> 1) * 64;
  const int m0 = blockIdx.y * 128, j0 = blockIdx.x * 128;
  const int cA0 = w*128 + lane,      cA1 = w*128 + 64 + lane;
  const int r0 = cA0>>2, o0 = swz_src_off(cA0), r1 = cA1>>2, o1 = swz_src_off(cA1);
  bf16* lA0 = As + (w*2+0)*512; bf16* lA1 = As + (w*2+1)*512;
  bf16* lB0 = Bs + (w*2+0)*512; bf16* lB1 = Bs + (w*2+1)*512;
  floatx4 acc[4][4] = {};
  for (int kb=0; kb<512; kb+=32){
    stage16(A + (size_t)(m0+r0)*512 + kb + o0, lA0);
    stage16(A + (size_t)(m0+r1)*512 + kb + o1, lA1);
    stage16(W + (size_t)(j0+r0)*512 + kb + o0, lB0);
    stage16(W + (size_t)(j0+r1)*512 + kb + o1, lB1);
    __syncthreads();
    short8 af[4], bfr[4];
    #pragma unroll
    for (int f=0; f<4; f++){
      af[f]  = *(const short8*)&As[swz_rd(mh + f*16 + lr, lq)];
      bfr[f] = *(const short8*)&Bs[swz_rd(jh + f*16 + lr, lq)];
    }
    #pragma unroll
    for (int mf=0; mf<4; mf++)
      #pragma unroll
      for (int jf=0; jf<4; jf++)
        acc[mf][jf] = MFMA16(af[mf], bfr[jf], acc[mf][jf]);
    __syncthreads();
  }
  #pragma unroll
  for (int mf=0; mf<4; mf++)
    #pragma unroll
    for (int jf=0; jf<4; jf++)
      #pragma unroll
      for (int i=0; i<4; i++){
        int m = m0 + mh + mf*16 + lq*4 + i;
        int j = j0 + jh + jf*16 + lr;
        Out[(size_t)m*512 + j] = __float2bfloat16(acc[mf][jf][i] + bias[j]);
      }
}

// ---------------- GI precompute: GI = AEb @ WaT + gate-bias, swizzled ----------------
__global__ __launch_bounds__(256) void k_giv2(
  const bf16* __restrict__ A, const bf16* __restrict__ W,
  const float* __restrict__ bih, const float* __restrict__ bhh,
  bf16* __restrict__ GI)
{
  __shared__ __align__(16) bf16 As[128*32];
  __shared__ __align__(16) bf16 Bs[128*32];
  const int tid = threadIdx.x, lane = tid & 63, w = tid >> 6;
  const int lr = lane & 15, lq = lane >> 4;
  const int mh = (w & 1) * 64, jh = (w >> 1) * 64;
  const int m0 = blockIdx.y * 128, j0 = blockIdx.x * 128;
  const int cA0 = w*128 + lane,      cA1 = w*128 + 64 + lane;
  const int r0 = cA0>>2, o0 = swz_src_off(cA0), r1 = cA1>>2, o1 = swz_src_off(cA1);
  bf16* lA0 = As + (w*2+0)*512; bf16* lA1 = As + (w*2+1)*512;
  bf16* lB0 = Bs + (w*2+0)*512; bf16* lB1 = Bs + (w*2+1)*512;
  floatx4 acc[4][4] = {};
  for (int kb=0; kb<512; kb+=32){
    stage16(A + (size_t)(m0+r0)*512 + kb + o0, lA0);
    stage16(A + (size_t)(m0+r1)*512 + kb + o1, lA1);
    stage16(W + (size_t)(j0+r0)*512 + kb + o0, lB0);
    stage16(W + (size_t)(j0+r1)*512 + kb + o1, lB1);
    __syncthreads();
    short8 af[4], bfr[4];
    #pragma unroll
    for (int f=0; f<4; f++){
      af[f]  = *(const short8*)&As[swz_rd(mh + f*16 + lr, lq)];
      bfr[f] = *(const short8*)&Bs[swz_rd(jh + f*16 + lr, lq)];
    }
    #pragma unroll
    for (int mf=0; mf<4; mf++)
      #pragma unroll
      for (int jf=0; jf<4; jf++)
        acc[mf][jf] = MFMA16(af[mf], bfr[jf], acc[mf][jf]);
    __syncthreads();
  }
  #pragma unroll
  for (int mf=0; mf<4; mf++)
    #pragma unroll
    for (int jf=0; jf<4; jf++)
      #pragma unroll
      for (int i=0; i<4; i++){
        int m = m0 + mh + mf*16 + lq*4 + i;
        int j = j0 + jh + jf*16 + lr;
        float bias = (j < 2048) ? (bih[j] + bhh[j]) : bih[j];
        GI[(size_t)m*3072 + j] = __float2bfloat16(acc[mf][jf][i] + bias);
      }
}

// ---------------- scan step kernels ----------------
// k_gru3: GI-based GRU. K=2048; waves own aligned 512-K slices. Epilogue split
// across all 4 waves (wave w handles acc element i=w; uniform branch, static idx).
__global__ __launch_bounds__(256) void k_gru3(
  const bf16* __restrict__ Z, const bf16* __restrict__ H,
  const bf16* __restrict__ GI,
  const bf16* __restrict__ WzT, const bf16* __restrict__ WhT,
  const float* __restrict__ bhh,
  bf16* __restrict__ Hn)
{
  __shared__ float red[4][3][64][4];
  const int tid = threadIdx.x, lane = tid & 63, w = tid >> 6;
  const int lr = lane & 15, lq = lane >> 4;
  const int j0 = (blockIdx.x & 63) * 16, m0 = (blockIdx.x >> 6) * 16;
  const int jl = j0 + lr;
  floatx4 A0={},A1={},A2={};     // R, U, (NX for w<2 | NH for w>=2)
  {
    const int kbase = (w & 1) * 512;
    const bf16* Ap = (w < 2 ? Z : H) + (size_t)(m0+lr)*1024 + kbase + lq*8;
    const bf16* Wt = (w < 2 ? WzT : WhT);
    const bf16* B0 = Wt + (size_t)jl*1024        + kbase + lq*8;
    const bf16* B1p= Wt + (size_t)(jl+1024)*1024 + kbase + lq*8;
    const bf16* B2p= Wt + (size_t)(jl+2048)*1024 + kbase + lq*8;
    #pragma unroll 4
    for (int k=0; k<512; k+=32){
      short8 a = ldf(Ap+k);
      A0 = MFMA16(a, ldf(B0+k),  A0);
      A1 = MFMA16(a, ldf(B1p+k), A1);
      A2 = MFMA16(a, ldf(B2p+k), A2);
    }
  }
  *(floatx4*)&red[w][0][lane][0]=A0;
  *(floatx4*)&red[w][1][lane][0]=A1;
  *(floatx4*)&red[w][2][lane][0]=A2;
  __syncthreads();
  {
    floatx4 sR={},sU={};
    #pragma unroll
    for (int ww=0;ww<4;ww++){
      sR += *(const floatx4*)&red[ww][0][lane][0];
      sU += *(const floatx4*)&red[ww][1][lane][0];
    }
    floatx4 sNX = *(const floatx4*)&red[0][2][lane][0];
    sNX        += *(const floatx4*)&red[1][2][lane][0];
    floatx4 sNH = *(const floatx4*)&red[2][2][lane][0];
    sNH        += *(const floatx4*)&red[3][2][lane][0];
    float vR, vU, vNX, vNH;
    if      (w==0){ vR=sR[0]; vU=sU[0]; vNX=sNX[0]; vNH=sNH[0]; }
    else if (w==1){ vR=sR[1]; vU=sU[1]; vNX=sNX[1]; vNH=sNH[1]; }
    else if (w==2){ vR=sR[2]; vU=sU[2]; vNX=sNX[2]; vNH=sNH[2]; }
    else          { vR=sR[3]; vU=sU[3]; vNX=sNX[3]; vNH=sNH[3]; }
    const int m = m0 + lq*4 + w;
    float bH = bhh[2048+jl];
    float gir = __bfloat162float(GI[(size_t)m*3072 + jl]);
    float giu = __bfloat162float(GI[(size_t)m*3072 + 1024 + jl]);
    float gin = __bfloat162float(GI[(size_t)m*3072 + 2048 + jl]);
    float r = fsig(vR + gir);
    float u = fsig(vU + giu);
    float n = ftanh(vNX + gin + r*(vNH + bH));
    float h = __bfloat162float(H[m*1024+jl]);
    Hn[m*1024+jl] = __float2bfloat16((1.f-u)*n + u*h);
  }
}

// k_gru2: verified AE-segment fallback (used only if workspace can't hold GI)
__global__ __launch_bounds__(256) void k_gru2(
  const bf16* __restrict__ Z, const bf16* __restrict__ H, const bf16* __restrict__ AE,
  const bf16* __restrict__ WzT, const bf16* __restrict__ WhT, const bf16* __restrict__ WaT,
  const float* __restrict__ bih, const float* __restrict__ bhh,
  bf16* __restrict__ Hn)
{
  __shared__ float red[4][4][64][4];
  const int tid = threadIdx.x, lane = tid & 63, w = tid >> 6;
  const int lr = lane & 15, lq = lane >> 4;
  const int j0 = (blockIdx.x & 63) * 16, m0 = (blockIdx.x >> 6) * 16;
  const int jl = j0 + lr;
  const int c0 = w*640, c1 = c0+640;
  floatx4 R={},U={},NX={},NH={};
  {
    int hi = c1 < 1024 ? c1 : 1024;
    for (int k=c0; k<hi; k+=32){
      short8 a = ldf(Z + (m0+lr)*1024 + k + lq*8);
      const bf16* bp = WzT + k + lq*8;
      R = MFMA16(a, ldf(bp + (size_t)jl*1024), R);
      U = MFMA16(a, ldf(bp + (size_t)(jl+1024)*1024), U);
      NX= MFMA16(a, ldf(bp + (size_t)(jl+2048)*1024), NX);
    }
  }
  {
    int lo = c0 > 1024 ? c0 : 1024;
    int hi = c1 < 1536 ? c1 : 1536;
    for (int k=lo; k<hi; k+=32){
      int kk = k - 1024;
      short8 a = ldf(AE + (m0+lr)*512 + kk + lq*8);
      const bf16* bp = WaT + kk + lq*8;
      R = MFMA16(a, ldf(bp + (size_t)jl*512), R);
      U = MFMA16(a, ldf(bp + (size_t)(jl+1024)*512), U);
      NX= MFMA16(a, ldf(bp + (size_t)(jl+2048)*512), NX);
    }
  }
  {
    int lo = c0 > 1536 ? c0 : 1536;
    for (int k=lo; k<c1; k+=32){
      int kk = k - 1536;
      short8 a = ldf(H + (m0+lr)*1024 + kk + lq*8);
      const bf16* bp = WhT + kk + lq*8;
      R = MFMA16(a, ldf(bp + (size_t)jl*1024), R);
      U = MFMA16(a, ldf(bp + (size_t)(jl+1024)*1024), U);
      NH= MFMA16(a, ldf(bp + (size_t)(jl+2048)*1024), NH);
    }
  }
  *(floatx4*)&red[w][0][lane][0]=R;
  *(floatx4*)&red[w][1][lane][0]=U;
  *(floatx4*)&red[w][2][lane][0]=NX;
  *(floatx4*)&red[w][3][lane][0]=NH;
  __syncthreads();
  if (w==0){
    floatx4 sR={},sU={},sNX={},sNH={};
    #pragma unroll
    for (int ww=0;ww<4;ww++){
      sR += *(const floatx4*)&red[ww][0][lane][0];
      sU += *(const floatx4*)&red[ww][1][lane][0];
      sNX+= *(const floatx4*)&red[ww][2][lane][0];
      sNH+= *(const floatx4*)&red[ww][3][lane][0];
    }
    float bR = bih[jl]+bhh[jl];
    float bU = bih[1024+jl]+bhh[1024+jl];
    float bX = bih[2048+jl], bH = bhh[2048+jl];
    #pragma unroll
    for (int i=0;i<4;i++){
      int m = m0 + lq*4 + i;
      float r = fsig(sR[i]+bR);
      float u = fsig(sU[i]+bU);
      float n = ftanh(sNX[i]+bX + r*(sNH[i]+bH));
      float h = __bfloat162float(H[m*1024+jl]);
      Hn[m*1024+jl] = __float2bfloat16((1.f-u)*n + u*h);
    }
  }
}

__global__ __launch_bounds__(256) void k_lsd1(
  const bf16* __restrict__ Hn, const bf16* __restrict__ Lw1,
  const float* __restrict__ Lb1, bf16* __restrict__ X)
{
  __shared__ float red[4][64][4];
  const int tid = threadIdx.x, lane = tid & 63, w = tid >> 6;
  const int lr = lane & 15, lq = lane >> 4;
  const int j0 = (blockIdx.x & 63) * 16, m0 = (blockIdx.x >> 6) * 16;
  const int jl = j0 + lr;
  floatx4 C={};
  const bf16* Ap = Hn + (m0+lr)*1024 + lq*8;
  const bf16* Bp = Lw1 + (size_t)jl*1024 + lq*8;
  #pragma unroll
  for (int k=w*256; k<w*256+256; k+=32)
    C = MFMA16(ldf(Ap+k), ldf(Bp+k), C);
  *(floatx4*)&red[w][lane][0] = C;
  __syncthreads();
  {
    floatx4 s={};
    #pragma unroll
    for (int ww=0;ww<4;ww++) s += *(const floatx4*)&red[ww][lane][0];
    float v;
    if      (w==0) v = s[0];
    else if (w==1) v = s[1];
    else if (w==2) v = s[2];
    else           v = s[3];
    const int m = m0 + lq*4 + w;
    X[m*1024+jl] = __float2bfloat16(ftanh(v + Lb1[jl]));
  }
}

__global__ __launch_bounds__(256) void k_lsd2(
  const bf16* __restrict__ X, const bf16* __restrict__ Lw2,
  const float* __restrict__ Lb2, const float* __restrict__ eps,
  bf16* __restrict__ Zn)
{
  __shared__ float red[4][2][64][4];
  const int tid = threadIdx.x, lane = tid & 63, w = tid >> 6;
  const int lr = lane & 15, lq = lane >> 4;
  const int j0 = (blockIdx.x & 63) * 16, m0 = (blockIdx.x >> 6) * 16;
  const int jl = j0 + lr;
  floatx4 M={}, L={};
  const bf16* Ap = X + (m0+lr)*1024 + lq*8;
  const bf16* Bm = Lw2 + (size_t)jl*1024 + lq*8;
  const bf16* Bl = Lw2 + (size_t)(1024+jl)*1024 + lq*8;
  #pragma unroll
  for (int k=w*256; k<w*256+256; k+=32){
    short8 a = ldf(Ap+k);
    M = MFMA16(a, ldf(Bm+k), M);
    L = MFMA16(a, ldf(Bl+k), L);
  }
  *(floatx4*)&red[w][0][lane][0] = M;
  *(floatx4*)&red[w][1][lane][0] = L;
  __syncthreads();
  {
    floatx4 sM={}, sL={};
    #pragma unroll
    for (int ww=0;ww<4;ww++){
      sM += *(const floatx4*)&red[ww][0][lane][0];
      sL += *(const floatx4*)&red[ww][1][lane][0];
    }
    float vM, vL;
    if      (w==0){ vM=sM[0]; vL=sL[0]; }
    else if (w==1){ vM=sM[1]; vL=sL[1]; }
    else if (w==2){ vM=sM[2]; vL=sL[2]; }
    else          { vM=sM[3]; vL=sL[3]; }
    const int m = m0 + lq*4 + w;
    float z = vM + Lb2[jl] + __expf(vL + Lb2[1024+jl]) * eps[m*1024+jl];
    Zn[m*1024+jl] = __float2bfloat16(z);
  }
}

// ---------------- decode: 128x128 LDS-tiled GEMM, swizzled ----------------
__global__ __launch_bounds__(256) void k_dec1v2(
  const bf16* __restrict__ Zb, const bf16* __restrict__ Hb,
  const bf16* __restrict__ W, const float* __restrict__ bias,
  bf16* __restrict__ Y)
{
  __shared__ __align__(16) bf16 As[128*32];
  __shared__ __align__(16) bf16 Bs[128*32];
  const int tid = threadIdx.x, lane = tid & 63, w = tid >> 6;
  const int lr = lane & 15, lq = lane >> 4;
  const int mh = (w & 1) * 64, jh = (w >> 1) * 64;
  const int m0 = blockIdx.y * 128, j0 = blockIdx.x * 128;
  const int cA0 = w*128 + lane,      cA1 = w*128 + 64 + lane;
  const int r0 = cA0>>2, o0 = swz_src_off(cA0), r1 = cA1>>2, o1 = swz_src_off(cA1);
  bf16* lA0 = As + (w*2+0)*512; bf16* lA1 = As + (w*2+1)*512;
  bf16* lB0 = Bs + (w*2+0)*512; bf16* lB1 = Bs + (w*2+1)*512;
  floatx4 acc[4][4] = {};
  const bf16* Aseg[2] = { Zb + 256*1024, Hb + 256*1024 };
  #pragma unroll
  for (int seg=0; seg<2; seg++){
    const bf16* A = Aseg[seg];
    const bf16* Wb = W + seg*1024;
    for (int kb=0; kb<1024; kb+=32){
      stage16(A  + (size_t)(m0+r0)*1024 + kb + o0, lA0);
      stage16(A  + (size_t)(m0+r1)*1024 + kb + o1, lA1);
      stage16(Wb + (size_t)(j0+r0)*2048 + kb + o0, lB0);
      stage16(Wb + (size_t)(j0+r1)*2048 + kb + o1, lB1);
      __syncthreads();
      short8 af[4], bfr[4];
      #pragma unroll
      for (int f=0; f<4; f++){
        af[f]  = *(const short8*)&As[swz_rd(mh + f*16 + lr, lq)];
        bfr[f] = *(const short8*)&Bs[swz_rd(jh + f*16 + lr, lq)];
      }
      #pragma unroll
      for (int mf=0; mf<4; mf++)
        #pragma unroll
        for (int jf=0; jf<4; jf++)
          acc[mf][jf] = MFMA16(af[mf], bfr[jf], acc[mf][jf]);
      __syncthreads();
    }
  }
  #pragma unroll
  for (int mf=0; mf<4; mf++)
    #pragma unroll
    for (int jf=0; jf<4; jf++)
      #pragma unroll
      for (int i=0; i<4; i++){
        int m = m0 + mh + mf*16 + lq*4 + i;
        int j = j0 + jh + jf*16 + lr;
        Y[(size_t)m*1024 + j] = __float2bfloat16(ftanh(acc[mf][jf][i] + bias[j]));
      }
}

__global__ __launch_bounds__(256) void k_out1v2(
  const bf16* __restrict__ Yb, const bf16* __restrict__ W,
  const float* __restrict__ bias, float* __restrict__ out)
{
  __shared__ __align__(16) bf16 As[128*32];
  __shared__ __align__(16) bf16 Bs[128*32];
  const int tid = threadIdx.x, lane = tid & 63, w = tid >> 6;
  const int lr = lane & 15, lq = lane >> 4;
  const int mh = (w & 1) * 64, jh = (w >> 1) * 64;
  const int m0 = blockIdx.y * 128, j0 = blockIdx.x * 128;
  const int cA0 = w*128 + lane,      cA1 = w*128 + 64 + lane;
  const int r0 = cA0>>2, o0 = swz_src_off(cA0), r1 = cA1>>2, o1 = swz_src_off(cA1);
  bf16* lA0 = As + (w*2+0)*512; bf16* lA1 = As + (w*2+1)*512;
  bf16* lB0 = Bs + (w*2+0)*512; bf16* lB1 = Bs + (w*2+1)*512;
  floatx4 acc[4][4] = {};
  for (int kb=0; kb<1024; kb+=32){
    stage16(Yb + (size_t)(m0+r0)*1024 + kb + o0, lA0);
    stage16(Yb + (size_t)(m0+r1)*1024 + kb + o1, lA1);
    stage16(W  + (size_t)(j0+r0)*1024 + kb + o0, lB0);
    stage16(W  + (size_t)(j0+r1)*1024 + kb + o1, lB1);
    __syncthreads();
    short8 af[4], bfr[4];
    #pragma unroll
    for (int f=0; f<4; f++){
      af[f]  = *(const short8*)&As[swz_rd(mh + f*16 + lr, lq)];
      bfr[f] = *(const short8*)&Bs[swz_rd(jh + f*16 + lr, lq)];
    }
    #pragma unroll
    for (int mf=0; mf<4; mf++)
      #pragma unroll
      for (int jf=0; jf<4; jf++)
        acc[mf][jf] = MFMA16(af[mf], bfr[jf], acc[mf][jf]);
    __syncthreads();
  }
  #pragma unroll
  for (int mf=0; mf<4; mf++)
    #pragma unroll
    for (int jf=0; jf<4; jf++)
      #pragma unroll
      for (int i=0; i<4; i++){
        int m = m0 + mh + mf*16 + lq*4 + i;
        int j = j0 + jh + jf*16 + lr;
        int b = m & 255, t = m >> 8;
        out[(size_t)b*40960 + t*640 + j] = acc[mf][jf][i] + bias[j];
      }
}

__global__ __launch_bounds__(256) void k_sd(
  const bf16* __restrict__ Zb, const bf16* __restrict__ Hb,
  const bf16* __restrict__ W, const float* __restrict__ bias,
  float* __restrict__ out)
{
  int lane = threadIdx.x & 63, wave = threadIdx.x >> 6;
  int lr = lane & 15, lq = lane >> 4;
  int m0 = blockIdx.x * 32;
  int j0 = wave * 16;
  floatx4 aM[2] = {}, aL[2] = {};
  const bf16* Az = Zb + 256*1024;
  const bf16* Ah = Hb + 256*1024;
  #pragma unroll 2
  for (int kb=0; kb<1024; kb+=32){
    short8 a0 = ldf(Az + (m0+lr)*1024 + kb + lq*8);
    short8 a1 = ldf(Az + (m0+16+lr)*1024 + kb + lq*8);
    short8 bm = ldf(W + (size_t)(j0+lr)*2048 + kb + lq*8);
    short8 bl = ldf(W + (size_t)(j0+64+lr)*2048 + kb + lq*8);
    aM[0] = MFMA16(a0,bm,aM[0]); aM[1] = MFMA16(a1,bm,aM[1]);
    aL[0] = MFMA16(a0,bl,aL[0]); aL[1] = MFMA16(a1,bl,aL[1]);
  }
  #pragma unroll 2
  for (int kb=0; kb<1024; kb+=32){
    short8 a0 = ldf(Ah + (m0+lr)*1024 + kb + lq*8);
    short8 a1 = ldf(Ah + (m0+16+lr)*1024 + kb + lq*8);
    short8 bm = ldf(W + (size_t)(j0+lr)*2048 + 1024 + kb + lq*8);
    short8 bl = ldf(W + (size_t)(j0+64+lr)*2048 + 1024 + kb + lq*8);
    aM[0] = MFMA16(a0,bm,aM[0]); aM[1] = MFMA16(a1,bm,aM[1]);
    aL[0] = MFMA16(a0,bl,aL[0]); aL[1] = MFMA16(a1,bl,aL[1]);
  }
  #pragma unroll
  for (int rf=0;rf<2;rf++)
    #pragma unroll
    for (int i=0;i<4;i++){
      int m = m0 + rf*16 + lq*4 + i;
      int j = j0 + lr;
      int b = m & 255, t = m >> 8;
      out[b*40960 + t*640 + 512 + j] = aM[rf][i] + bias[j];
      out[b*40960 + t*640 + 576 + j] = __expf(aL[rf][i] + bias[64+j]);
    }
}

extern "C" void kernel_launch(void* const* d_in, const int* in_sizes, int n_in,
                              void* d_out, int out_size, void* d_ws, size_t ws_size,
                              hipStream_t stream)
{
  const float* obs    = (const float*)d_in[0];
  const float* state  = (const float*)d_in[1];
  const float* act    = (const float*)d_in[2];
  const float* eps0   = (const float*)d_in[3];
  const float* epss   = (const float*)d_in[4];
  const float* enc_w1 = (const float*)d_in[5];  const float* enc_b1 = (const float*)d_in[6];
  const float* enc_w2 = (const float*)d_in[7];  const float* enc_b2 = (const float*)d_in[8];
  const float* post_w1= (const float*)d_in[9];  const float* post_b1= (const float*)d_in[10];
  const float* post_w2= (const float*)d_in[11]; const float* post_b2= (const float*)d_in[12];
  const float* amlp_w1= (const float*)d_in[13]; const float* amlp_b1= (const float*)d_in[14];
  const float* amlp_w2= (const float*)d_in[15]; const float* amlp_b2= (const float*)d_in[16];
  const float* gwih   = (const float*)d_in[17];
  const float* gwhh   = (const float*)d_in[18];
  const float* gbih   = (const float*)d_in[19];
  const float* gbhh   = (const float*)d_in[20];
  const float* lsd_w1 = (const float*)d_in[21]; const float* lsd_b1 = (const float*)d_in[22];
  const float* lsd_w2 = (const float*)d_in[23]; const float* lsd_b2 = (const float*)d_in[24];
  const float* dec_w1 = (const float*)d_in[25]; const float* dec_b1 = (const float*)d_in[26];
  const float* dec_w2 = (const float*)d_in[27]; const float* dec_b2 = (const float*)d_in[28];
  const float* sd_w   = (const float*)d_in[29]; const float* sd_b   = (const float*)d_in[30];
  float* out = (float*)d_out;

  char* w = (char*)d_ws;
  size_t off = 0;
  auto alloc = [&](size_t elems)->bf16* {
    bf16* p = (bf16*)(w + off);
    off += ((elems*2 + 255)/256)*256;
    return p;
  };
  bf16* WzT      = alloc((size_t)3072*1024);
  bf16* WhT      = alloc((size_t)3072*1024);
  bf16* WaT      = alloc((size_t)3072*512);
  bf16* lsd_w1T  = alloc((size_t)1024*1024);
  bf16* lsd_w2T  = alloc((size_t)2048*1024);
  bf16* dec_w1T  = alloc((size_t)1024*2048);
  bf16* dec_w2T  = alloc((size_t)512*1024);
  bf16* sd_wT    = alloc((size_t)128*2048);
  bf16* enc_w1T  = alloc((size_t)512*512);
  bf16* enc_w2T  = alloc((size_t)256*512);
  bf16* post_w1sT= alloc((size_t)1024*192);
  bf16* post_w2T = alloc((size_t)2048*1024);
  bf16* amlp_w2T = alloc((size_t)512*512);
  bf16* obsb     = alloc((size_t)256*512);
  bf16* E1       = alloc((size_t)256*512);
  bf16* PIN      = alloc((size_t)256*192);
  bf16* P1       = alloc((size_t)256*1024);
  bf16* X        = alloc((size_t)256*1024);
  bf16* Zbuf     = alloc((size_t)65*256*1024);
  bf16* Hbuf     = alloc((size_t)65*256*1024);
  bf16* AEb      = alloc((size_t)16384*512);
  bf16* R        = alloc((size_t)16384*3072);   // union region: H1 / GI / Y1
  bf16* Y1       = R;
  bf16* GI       = R;
  bf16* H1       = R;      // H1 dead before GI written; GI dead before Y1 written
  const bool useGI = (ws_size >= off);

  // --- weight prep: ONE fused transpose launch ---
  TPJobs jobs;
  jobs.src[0]=enc_w1;  jobs.dst[0]=enc_w1T;
  jobs.src[1]=enc_w2;  jobs.dst[1]=enc_w2T;
  jobs.src[2]=post_w1 + (size_t)1024*1024; jobs.dst[2]=post_w1sT;
  jobs.src[3]=post_w2; jobs.dst[3]=post_w2T;
  jobs.src[4]=amlp_w2; jobs.dst[4]=amlp_w2T;
  jobs.src[5]=gwih;    jobs.dst[5]=WzT;
  jobs.src[6]=gwih + (size_t)1024*3072; jobs.dst[6]=WaT;
  jobs.src[7]=gwhh;    jobs.dst[7]=WhT;
  jobs.src[8]=lsd_w1;  jobs.dst[8]=lsd_w1T;
  jobs.src[9]=lsd_w2;  jobs.dst[9]=lsd_w2T;
  jobs.src[10]=dec_w1; jobs.dst[10]=dec_w1T;
  jobs.src[11]=dec_w2; jobs.dst[11]=dec_w2T;
  jobs.src[12]=sd_w;   jobs.dst[12]=sd_wT;
  k_transpose_all<<<16448,256,0,stream>>>(jobs);

  k_cast<<<512,256,0,stream>>>(obs, obsb, 256*512);
  k_cast_state<<<64,256,0,stream>>>(state, PIN);
  k_acth1<<<32768,256,0,stream>>>(act, amlp_w1, amlp_b1, H1);

  hipMemsetAsync(Hbuf, 0, (size_t)256*1024*2, stream);

  k_gemm16<<<dim3(8,16),256,0,stream>>>(obsb, 512, enc_w1T, enc_b1, E1, 512, 0, 512, 1);
  k_gemm16<<<dim3(2,16),256,0,stream>>>(E1, 512, enc_w2T, enc_b2, PIN, 192, 64, 512, 0);
  k_gemm16<<<dim3(16,16),256,0,stream>>>(PIN, 192, post_w1sT, post_b1, P1, 1024, 0, 192, 1);
  k_gauss<<<dim3(16,16),256,0,stream>>>(P1, post_w2T, post_b2, eps0, Zbuf, 1024);
  k_aev2<<<dim3(4,128),256,0,stream>>>(H1, amlp_w2T, amlp_b2, AEb);
  if (useGI)
    k_giv2<<<dim3(24,128),256,0,stream>>>(AEb, WaT, gbih, gbhh, GI);  // overwrites H1 (dead)

  // --- sequential scan: 3 kernels per step, launches are the sync mechanism ---
  for (int t=0; t<64; t++){
    const bf16* Zt = Zbuf + (size_t)t*262144;
    const bf16* Ht = Hbuf + (size_t)t*262144;
    bf16* Htn = Hbuf + (size_t)(t+1)*262144;
    bf16* Ztn = Zbuf + (size_t)(t+1)*262144;
    if (useGI)
      k_gru3<<<1024,256,0,stream>>>(Zt, Ht, GI + (size_t)t*256*3072, WzT, WhT, gbhh, Htn);
    else
      k_gru2<<<1024,256,0,stream>>>(Zt, Ht, AEb + (size_t)t*131072, WzT, WhT, WaT, gbih, gbhh, Htn);
    k_lsd1<<<1024,256,0,stream>>>(Htn, lsd_w1T, lsd_b1, X);
    k_lsd2<<<1024,256,0,stream>>>(X, lsd_w2T, lsd_b2, epss + (size_t)t*262144, Ztn);
  }

  // --- decode (Y1 overwrites GI region — GI dead after scan) ---
  k_dec1v2<<<dim3(8,128),256,0,stream>>>(Zbuf, Hbuf, dec_w1T, dec_b1, Y1);
  k_out1v2<<<dim3(4,128),256,0,stream>>>(Y1, dec_w2T, dec_b2, out);
  k_sd<<<512,256,0,stream>>>(Zbuf, Hbuf, sd_wT, sd_b, out);
}

// Round 6
// 3032.610 us; speedup vs baseline: 4.9865x; 1.3203x over previous
//
#include <hip/hip_runtime.h>
#include <hip/hip_bf16.h>

typedef __attribute__((ext_vector_type(8))) short short8;
typedef __attribute__((ext_vector_type(4))) float floatx4;
typedef __hip_bfloat16 bf16;

#define MFMA16(a,b,c) __builtin_amdgcn_mfma_f32_16x16x32_bf16((a),(b),(c),0,0,0)

__device__ __forceinline__ short8 ldf(const bf16* p){ return *(const short8*)p; }
__device__ __forceinline__ float fsig(float x){ return 1.f/(1.f+__expf(-x)); }
__device__ __forceinline__ float ftanh(float x){
  float c = fminf(fmaxf(x,-15.f),15.f);
  float e = __expf(2.f*c);
  return (e-1.f)/(e+1.f);
}

typedef __attribute__((address_space(1))) void gvoid;
typedef __attribute__((address_space(3))) void lvoid;
__device__ __forceinline__ void stage16(const bf16* g, bf16* l){
  __builtin_amdgcn_global_load_lds((gvoid*)g, (lvoid*)l, 16, 0, 0);
}

// LDS [128][32]bf16 swizzle (r5, verified: conflicts 8.39M -> 0):
__device__ __forceinline__ int swz_src_off(int c){
  return (((c & 3) ^ ((c >> 3) & 3)) << 3);
}
__device__ __forceinline__ int swz_rd(int row, int lq){
  return row*32 + (((lq ^ (row >> 1)) & 3) << 3);
}

// ---------------- fused weight prep: 13 transposes in ONE launch ----------------
struct TPJobs { const float* src[13]; bf16* dst[13]; };

__global__ __launch_bounds__(256) void k_transpose_all(TPJobs jobs){
  const int RR[13]  = {512,512,192,1024,512,1024,512,1024,1024,1024,2048,1024,2048};
  const int CCv[13] = {512,256,1024,2048,512,3072,3072,3072,1024,2048,1024,512,128};
  const int PFX[14] = {0,256,384,576,2624,2880,5952,7488,10560,11584,13632,15680,16192,16448};
  int b = blockIdx.x;
  int j = 0;
  #pragma unroll
  for (int i=0;i<13;i++) if (b >= PFX[i+1]) j = i+1;
  const int local = b - PFX[j];
  const int C = CCv[j], R = RR[j];
  const int cw = C >> 5;
  const int bx = local % cw, by = local / cw;
  const float* in = jobs.src[j];
  bf16* out = jobs.dst[j];
  __shared__ float t[32][33];
  int bc = bx*32, br = by*32;
  int tx = threadIdx.x & 31, ty = threadIdx.x >> 5;
  #pragma unroll
  for (int i=0;i<32;i+=8) t[ty+i][tx] = in[(size_t)(br+ty+i)*C + bc+tx];
  __syncthreads();
  #pragma unroll
  for (int i=0;i<32;i+=8) out[(size_t)(bc+ty+i)*R + br+tx] = __float2bfloat16(t[tx][ty+i]);
}

__global__ __launch_bounds__(256) void k_cast(const float* __restrict__ in, bf16* __restrict__ out, int n){
  int i = blockIdx.x*256+threadIdx.x;
  if (i<n) out[i] = __float2bfloat16(in[i]);
}

__global__ __launch_bounds__(256) void k_cast_state(const float* __restrict__ st, bf16* __restrict__ pin){
  int i = blockIdx.x*256+threadIdx.x; // 16384
  int r = i >> 6, c = i & 63;
  pin[r*192 + c] = __float2bfloat16(st[i]);
}

__global__ __launch_bounds__(256) void k_acth1(const float* __restrict__ act,
                                               const float* __restrict__ w1,
                                               const float* __restrict__ b1,
                                               bf16* __restrict__ H1){
  int idx = blockIdx.x*256 + threadIdx.x;
  int c = idx & 511; int r = idx >> 9;
  int t = r >> 8, b = r & 255;
  const float* a = act + (b*64 + t)*6;
  float s = b1[c];
  #pragma unroll
  for (int i=0;i<6;i++) s += a[i]*w1[i*512+c];
  H1[r*512+c] = __float2bfloat16(ftanh(s));
}

// ---------------- generic GEMM (setup path only, small shapes) ----------------
__global__ __launch_bounds__(256) void k_gemm16(
  const bf16* __restrict__ A, int sA,
  const bf16* __restrict__ Bt,
  const float* __restrict__ bias,
  bf16* __restrict__ out, int sO, int oO,
  int K, int mode)
{
  int lane = threadIdx.x & 63, wave = threadIdx.x >> 6;
  int lr = lane & 15, lq = lane >> 4;
  int j0 = blockIdx.x*64 + wave*16;
  int m0 = blockIdx.y*16;
  const bf16* Ap = A + (m0+lr)*sA + lq*8;
  const bf16* Bp = Bt + (j0+lr)*K + lq*8;
  floatx4 acc = {0.f,0.f,0.f,0.f};
  #pragma unroll 4
  for (int kb=0; kb<K; kb+=32){
    short8 a = ldf(Ap+kb);
    short8 b = ldf(Bp+kb);
    acc = MFMA16(a, b, acc);
  }
  #pragma unroll
  for (int i=0;i<4;i++){
    int m = m0 + lq*4 + i, j = j0 + lr;
    float v = acc[i] + bias[j];
    if (mode) v = ftanh(v);
    out[m*sO + oO + j] = __float2bfloat16(v);
  }
}

// ---------------- gaussian head (setup: z0) ----------------
__global__ __launch_bounds__(256) void k_gauss(
  const bf16* __restrict__ A, const bf16* __restrict__ Bt,
  const float* __restrict__ bias, const float* __restrict__ eps,
  bf16* __restrict__ out, int K)
{
  int lane = threadIdx.x & 63, wave = threadIdx.x >> 6;
  int lr = lane & 15, lq = lane >> 4;
  int j0 = blockIdx.x*64 + wave*16;
  int m0 = blockIdx.y*16;
  const bf16* Ap = A + (m0+lr)*K + lq*8;
  const bf16* Bm = Bt + (j0+lr)*K + lq*8;
  const bf16* Bl = Bt + (j0+1024+lr)*K + lq*8;
  floatx4 aM = {0.f,0.f,0.f,0.f}, aL = {0.f,0.f,0.f,0.f};
  #pragma unroll 4
  for (int kb=0;kb<K;kb+=32){
    short8 a = ldf(Ap+kb);
    aM = MFMA16(a, ldf(Bm+kb), aM);
    aL = MFMA16(a, ldf(Bl+kb), aL);
  }
  #pragma unroll
  for (int i=0;i<4;i++){
    int m = m0+lq*4+i, j = j0+lr;
    float z = aM[i] + bias[j] + __expf(aL[i] + bias[1024+j]) * eps[m*1024 + j];
    out[m*1024+j] = __float2bfloat16(z);
  }
}

// ---------------- AE gemm: 128x128 LDS tile, swizzled. grid (128,4): m = x so
// same-m j-blocks share id%8 -> same XCD -> A panel fetched once per XCD. ----
__global__ __launch_bounds__(256) void k_aev2(
  const bf16* __restrict__ A, const bf16* __restrict__ W,
  const float* __restrict__ bias, bf16* __restrict__ Out)
{
  __shared__ __align__(16) bf16 As[128*32];
  __shared__ __align__(16) bf16 Bs[128*32];
  const int tid = threadIdx.x, lane = tid & 63, w = tid >> 6;
  const int lr = lane & 15, lq = lane >> 4;
  const int mh = (w & 1) * 64, jh = (w >> 1) * 64;
  const int m0 = blockIdx.x * 128, j0 = blockIdx.y * 128;
  const int cA0 = w*128 + lane,      cA1 = w*128 + 64 + lane;
  const int r0 = cA0>>2, o0 = swz_src_off(cA0), r1 = cA1>>2, o1 = swz_src_off(cA1);
  bf16* lA0 = As + (w*2+0)*512; bf16* lA1 = As + (w*2+1)*512;
  bf16* lB0 = Bs + (w*2+0)*512; bf16* lB1 = Bs + (w*2+1)*512;
  floatx4 acc[4][4] = {};
  for (int kb=0; kb<512; kb+=32){
    stage16(A + (size_t)(m0+r0)*512 + kb + o0, lA0);
    stage16(A + (size_t)(m0+r1)*512 + kb + o1, lA1);
    stage16(W + (size_t)(j0+r0)*512 + kb + o0, lB0);
    stage16(W + (size_t)(j0+r1)*512 + kb + o1, lB1);
    __syncthreads();
    short8 af[4], bfr[4];
    #pragma unroll
    for (int f=0; f<4; f++){
      af[f]  = *(const short8*)&As[swz_rd(mh + f*16 + lr, lq)];
      bfr[f] = *(const short8*)&Bs[swz_rd(jh + f*16 + lr, lq)];
    }
    #pragma unroll
    for (int mf=0; mf<4; mf++)
      #pragma unroll
      for (int jf=0; jf<4; jf++)
        acc[mf][jf] = MFMA16(af[mf], bfr[jf], acc[mf][jf]);
    __syncthreads();
  }
  #pragma unroll
  for (int mf=0; mf<4; mf++)
    #pragma unroll
    for (int jf=0; jf<4; jf++)
      #pragma unroll
      for (int i=0; i<4; i++){
        int m = m0 + mh + mf*16 + lq*4 + i;
        int j = j0 + jh + jf*16 + lr;
        Out[(size_t)m*512 + j] = __float2bfloat16(acc[mf][jf][i] + bias[j]);
      }
}

// ---------------- GI precompute, swizzled, grid (128,24) ----------------
__global__ __launch_bounds__(256) void k_giv2(
  const bf16* __restrict__ A, const bf16* __restrict__ W,
  const float* __restrict__ bih, const float* __restrict__ bhh,
  bf16* __restrict__ GI)
{
  __shared__ __align__(16) bf16 As[128*32];
  __shared__ __align__(16) bf16 Bs[128*32];
  const int tid = threadIdx.x, lane = tid & 63, w = tid >> 6;
  const int lr = lane & 15, lq = lane >> 4;
  const int mh = (w & 1) * 64, jh = (w >> 1) * 64;
  const int m0 = blockIdx.x * 128, j0 = blockIdx.y * 128;
  const int cA0 = w*128 + lane,      cA1 = w*128 + 64 + lane;
  const int r0 = cA0>>2, o0 = swz_src_off(cA0), r1 = cA1>>2, o1 = swz_src_off(cA1);
  bf16* lA0 = As + (w*2+0)*512; bf16* lA1 = As + (w*2+1)*512;
  bf16* lB0 = Bs + (w*2+0)*512; bf16* lB1 = Bs + (w*2+1)*512;
  floatx4 acc[4][4] = {};
  for (int kb=0; kb<512; kb+=32){
    stage16(A + (size_t)(m0+r0)*512 + kb + o0, lA0);
    stage16(A + (size_t)(m0+r1)*512 + kb + o1, lA1);
    stage16(W + (size_t)(j0+r0)*512 + kb + o0, lB0);
    stage16(W + (size_t)(j0+r1)*512 + kb + o1, lB1);
    __syncthreads();
    short8 af[4], bfr[4];
    #pragma unroll
    for (int f=0; f<4; f++){
      af[f]  = *(const short8*)&As[swz_rd(mh + f*16 + lr, lq)];
      bfr[f] = *(const short8*)&Bs[swz_rd(jh + f*16 + lr, lq)];
    }
    #pragma unroll
    for (int mf=0; mf<4; mf++)
      #pragma unroll
      for (int jf=0; jf<4; jf++)
        acc[mf][jf] = MFMA16(af[mf], bfr[jf], acc[mf][jf]);
    __syncthreads();
  }
  #pragma unroll
  for (int mf=0; mf<4; mf++)
    #pragma unroll
    for (int jf=0; jf<4; jf++)
      #pragma unroll
      for (int i=0; i<4; i++){
        int m = m0 + mh + mf*16 + lq*4 + i;
        int j = j0 + jh + jf*16 + lr;
        float bias = (j < 2048) ? (bih[j] + bhh[j]) : bih[j];
        GI[(size_t)m*3072 + j] = __float2bfloat16(acc[mf][jf][i] + bias);
      }
}

// ---------------- scan step kernels: 512 blocks, 32-row m-tiles ----------------
// B-rows are loaded once per block regardless of m-rows -> 32m halves the
// per-dispatch weight (B) traffic vs 16m at same j decomposition (scan kernels
// are L2-BW-bound on B reads). bid&63 = jt keeps jt%8 = XCD.
__global__ __launch_bounds__(256) void k_gru3(
  const bf16* __restrict__ Z, const bf16* __restrict__ H,
  const bf16* __restrict__ GI,
  const bf16* __restrict__ WzT, const bf16* __restrict__ WhT,
  const float* __restrict__ bhh,
  bf16* __restrict__ Hn)
{
  __shared__ float red[4][3][2][64][4];
  const int tid = threadIdx.x, lane = tid & 63, w = tid >> 6;
  const int lr = lane & 15, lq = lane >> 4;
  const int j0 = (blockIdx.x & 63) * 16, m0 = (blockIdx.x >> 6) * 32;
  const int jl = j0 + lr;
  floatx4 A0[2]={}, A1[2]={}, A2[2]={};   // R, U, (NX | NH) x 2 m-subtiles
  {
    const int kbase = (w & 1) * 512;
    const bf16* base = (w < 2 ? Z : H);
    const bf16* Ap0 = base + (size_t)(m0+lr)*1024 + kbase + lq*8;
    const bf16* Ap1 = Ap0 + 16*1024;
    const bf16* Wt = (w < 2 ? WzT : WhT);
    const bf16* B0 = Wt + (size_t)jl*1024        + kbase + lq*8;
    const bf16* B1p= Wt + (size_t)(jl+1024)*1024 + kbase + lq*8;
    const bf16* B2p= Wt + (size_t)(jl+2048)*1024 + kbase + lq*8;
    #pragma unroll 2
    for (int k=0; k<512; k+=32){
      short8 a0 = ldf(Ap0+k), a1 = ldf(Ap1+k);
      short8 b0 = ldf(B0+k), b1 = ldf(B1p+k), b2 = ldf(B2p+k);
      A0[0]=MFMA16(a0,b0,A0[0]); A0[1]=MFMA16(a1,b0,A0[1]);
      A1[0]=MFMA16(a0,b1,A1[0]); A1[1]=MFMA16(a1,b1,A1[1]);
      A2[0]=MFMA16(a0,b2,A2[0]); A2[1]=MFMA16(a1,b2,A2[1]);
    }
  }
  #pragma unroll
  for (int s=0;s<2;s++){
    *(floatx4*)&red[w][0][s][lane][0]=A0[s];
    *(floatx4*)&red[w][1][s][lane][0]=A1[s];
    *(floatx4*)&red[w][2][s][lane][0]=A2[s];
  }
  __syncthreads();
  const float bH = bhh[2048+jl];
  #pragma unroll
  for (int s=0;s<2;s++){
    floatx4 sR={},sU={};
    #pragma unroll
    for (int ww=0;ww<4;ww++){
      sR += *(const floatx4*)&red[ww][0][s][lane][0];
      sU += *(const floatx4*)&red[ww][1][s][lane][0];
    }
    floatx4 sNX = *(const floatx4*)&red[0][2][s][lane][0];
    sNX        += *(const floatx4*)&red[1][2][s][lane][0];
    floatx4 sNH = *(const floatx4*)&red[2][2][s][lane][0];
    sNH        += *(const floatx4*)&red[3][2][s][lane][0];
    float vR, vU, vNX, vNH;
    if      (w==0){ vR=sR[0]; vU=sU[0]; vNX=sNX[0]; vNH=sNH[0]; }
    else if (w==1){ vR=sR[1]; vU=sU[1]; vNX=sNX[1]; vNH=sNH[1]; }
    else if (w==2){ vR=sR[2]; vU=sU[2]; vNX=sNX[2]; vNH=sNH[2]; }
    else          { vR=sR[3]; vU=sU[3]; vNX=sNX[3]; vNH=sNH[3]; }
    const int m = m0 + s*16 + lq*4 + w;
    float gir = __bfloat162float(GI[(size_t)m*3072 + jl]);
    float giu = __bfloat162float(GI[(size_t)m*3072 + 1024 + jl]);
    float gin = __bfloat162float(GI[(size_t)m*3072 + 2048 + jl]);
    float r = fsig(vR + gir);
    float u = fsig(vU + giu);
    float n = ftanh(vNX + gin + r*(vNH + bH));
    float h = __bfloat162float(H[m*1024+jl]);
    Hn[m*1024+jl] = __float2bfloat16((1.f-u)*n + u*h);
  }
}

// k_gru2: verified AE-segment fallback (1024 blocks; used only if no GI space)
__global__ __launch_bounds__(256) void k_gru2(
  const bf16* __restrict__ Z, const bf16* __restrict__ H, const bf16* __restrict__ AE,
  const bf16* __restrict__ WzT, const bf16* __restrict__ WhT, const bf16* __restrict__ WaT,
  const float* __restrict__ bih, const float* __restrict__ bhh,
  bf16* __restrict__ Hn)
{
  __shared__ float red[4][4][64][4];
  const int tid = threadIdx.x, lane = tid & 63, w = tid >> 6;
  const int lr = lane & 15, lq = lane >> 4;
  const int j0 = (blockIdx.x & 63) * 16, m0 = (blockIdx.x >> 6) * 16;
  const int jl = j0 + lr;
  const int c0 = w*640, c1 = c0+640;
  floatx4 R={},U={},NX={},NH={};
  {
    int hi = c1 < 1024 ? c1 : 1024;
    for (int k=c0; k<hi; k+=32){
      short8 a = ldf(Z + (m0+lr)*1024 + k + lq*8);
      const bf16* bp = WzT + k + lq*8;
      R = MFMA16(a, ldf(bp + (size_t)jl*1024), R);
      U = MFMA16(a, ldf(bp + (size_t)(jl+1024)*1024), U);
      NX= MFMA16(a, ldf(bp + (size_t)(jl+2048)*1024), NX);
    }
  }
  {
    int lo = c0 > 1024 ? c0 : 1024;
    int hi = c1 < 1536 ? c1 : 1536;
    for (int k=lo; k<hi; k+=32){
      int kk = k - 1024;
      short8 a = ldf(AE + (m0+lr)*512 + kk + lq*8);
      const bf16* bp = WaT + kk + lq*8;
      R = MFMA16(a, ldf(bp + (size_t)jl*512), R);
      U = MFMA16(a, ldf(bp + (size_t)(jl+1024)*512), U);
      NX= MFMA16(a, ldf(bp + (size_t)(jl+2048)*512), NX);
    }
  }
  {
    int lo = c0 > 1536 ? c0 : 1536;
    for (int k=lo; k<c1; k+=32){
      int kk = k - 1536;
      short8 a = ldf(H + (m0+lr)*1024 + kk + lq*8);
      const bf16* bp = WhT + kk + lq*8;
      R = MFMA16(a, ldf(bp + (size_t)jl*1024), R);
      U = MFMA16(a, ldf(bp + (size_t)(jl+1024)*1024), U);
      NH= MFMA16(a, ldf(bp + (size_t)(jl+2048)*1024), NH);
    }
  }
  *(floatx4*)&red[w][0][lane][0]=R;
  *(floatx4*)&red[w][1][lane][0]=U;
  *(floatx4*)&red[w][2][lane][0]=NX;
  *(floatx4*)&red[w][3][lane][0]=NH;
  __syncthreads();
  if (w==0){
    floatx4 sR={},sU={},sNX={},sNH={};
    #pragma unroll
    for (int ww=0;ww<4;ww++){
      sR += *(const floatx4*)&red[ww][0][lane][0];
      sU += *(const floatx4*)&red[ww][1][lane][0];
      sNX+= *(const floatx4*)&red[ww][2][lane][0];
      sNH+= *(const floatx4*)&red[ww][3][lane][0];
    }
    float bR = bih[jl]+bhh[jl];
    float bU = bih[1024+jl]+bhh[1024+jl];
    float bX = bih[2048+jl], bH = bhh[2048+jl];
    #pragma unroll
    for (int i=0;i<4;i++){
      int m = m0 + lq*4 + i;
      float r = fsig(sR[i]+bR);
      float u = fsig(sU[i]+bU);
      float n = ftanh(sNX[i]+bX + r*(sNH[i]+bH));
      float h = __bfloat162float(H[m*1024+jl]);
      Hn[m*1024+jl] = __float2bfloat16((1.f-u)*n + u*h);
    }
  }
}

__global__ __launch_bounds__(256) void k_lsd1(
  const bf16* __restrict__ Hn, const bf16* __restrict__ Lw1,
  const float* __restrict__ Lb1, bf16* __restrict__ X)
{
  __shared__ float red[4][2][64][4];
  const int tid = threadIdx.x, lane = tid & 63, w = tid >> 6;
  const int lr = lane & 15, lq = lane >> 4;
  const int j0 = (blockIdx.x & 63) * 16, m0 = (blockIdx.x >> 6) * 32;
  const int jl = j0 + lr;
  floatx4 C[2]={};
  const bf16* Ap0 = Hn + (size_t)(m0+lr)*1024 + lq*8;
  const bf16* Ap1 = Ap0 + 16*1024;
  const bf16* Bp = Lw1 + (size_t)jl*1024 + lq*8;
  #pragma unroll
  for (int k=w*256; k<w*256+256; k+=32){
    short8 b = ldf(Bp+k);
    C[0] = MFMA16(ldf(Ap0+k), b, C[0]);
    C[1] = MFMA16(ldf(Ap1+k), b, C[1]);
  }
  *(floatx4*)&red[w][0][lane][0] = C[0];
  *(floatx4*)&red[w][1][lane][0] = C[1];
  __syncthreads();
  const float bb = Lb1[jl];
  #pragma unroll
  for (int s=0;s<2;s++){
    floatx4 sum={};
    #pragma unroll
    for (int ww=0;ww<4;ww++) sum += *(const floatx4*)&red[ww][s][lane][0];
    float v;
    if      (w==0) v = sum[0];
    else if (w==1) v = sum[1];
    else if (w==2) v = sum[2];
    else           v = sum[3];
    const int m = m0 + s*16 + lq*4 + w;
    X[m*1024+jl] = __float2bfloat16(ftanh(v + bb));
  }
}

__global__ __launch_bounds__(256) void k_lsd2(
  const bf16* __restrict__ X, const bf16* __restrict__ Lw2,
  const float* __restrict__ Lb2, const float* __restrict__ eps,
  bf16* __restrict__ Zn)
{
  __shared__ float red[4][2][2][64][4];   // [wave][head][sub][lane][4]
  const int tid = threadIdx.x, lane = tid & 63, w = tid >> 6;
  const int lr = lane & 15, lq = lane >> 4;
  const int j0 = (blockIdx.x & 63) * 16, m0 = (blockIdx.x >> 6) * 32;
  const int jl = j0 + lr;
  floatx4 M[2]={}, L[2]={};
  const bf16* Ap0 = X + (size_t)(m0+lr)*1024 + lq*8;
  const bf16* Ap1 = Ap0 + 16*1024;
  const bf16* Bm = Lw2 + (size_t)jl*1024 + lq*8;
  const bf16* Bl = Lw2 + (size_t)(1024+jl)*1024 + lq*8;
  #pragma unroll
  for (int k=w*256; k<w*256+256; k+=32){
    short8 a0 = ldf(Ap0+k), a1 = ldf(Ap1+k);
    short8 bm = ldf(Bm+k), bl = ldf(Bl+k);
    M[0] = MFMA16(a0, bm, M[0]); M[1] = MFMA16(a1, bm, M[1]);
    L[0] = MFMA16(a0, bl, L[0]); L[1] = MFMA16(a1, bl, L[1]);
  }
  #pragma unroll
  for (int s=0;s<2;s++){
    *(floatx4*)&red[w][0][s][lane][0] = M[s];
    *(floatx4*)&red[w][1][s][lane][0] = L[s];
  }
  __syncthreads();
  const float bmu = Lb2[jl], bls = Lb2[1024+jl];
  #pragma unroll
  for (int s=0;s<2;s++){
    floatx4 sM={}, sL={};
    #pragma unroll
    for (int ww=0;ww<4;ww++){
      sM += *(const floatx4*)&red[ww][0][s][lane][0];
      sL += *(const floatx4*)&red[ww][1][s][lane][0];
    }
    float vM, vL;
    if      (w==0){ vM=sM[0]; vL=sL[0]; }
    else if (w==1){ vM=sM[1]; vL=sL[1]; }
    else if (w==2){ vM=sM[2]; vL=sL[2]; }
    else          { vM=sM[3]; vL=sL[3]; }
    const int m = m0 + s*16 + lq*4 + w;
    float z = vM + bmu + __expf(vL + bls) * eps[m*1024+jl];
    Zn[m*1024+jl] = __float2bfloat16(z);
  }
}

// ---------------- decode: 128x128 LDS-tiled GEMM, swizzled, grid (128,8) ----
__global__ __launch_bounds__(256) void k_dec1v2(
  const bf16* __restrict__ Zb, const bf16* __restrict__ Hb,
  const bf16* __restrict__ W, const float* __restrict__ bias,
  bf16* __restrict__ Y)
{
  __shared__ __align__(16) bf16 As[128*32];
  __shared__ __align__(16) bf16 Bs[128*32];
  const int tid = threadIdx.x, lane = tid & 63, w = tid >> 6;
  const int lr = lane & 15, lq = lane >> 4;
  const int mh = (w & 1) * 64, jh = (w >> 1) * 64;
  const int m0 = blockIdx.x * 128, j0 = blockIdx.y * 128;
  const int cA0 = w*128 + lane,      cA1 = w*128 + 64 + lane;
  const int r0 = cA0>>2, o0 = swz_src_off(cA0), r1 = cA1>>2, o1 = swz_src_off(cA1);
  bf16* lA0 = As + (w*2+0)*512; bf16* lA1 = As + (w*2+1)*512;
  bf16* lB0 = Bs + (w*2+0)*512; bf16* lB1 = Bs + (w*2+1)*512;
  floatx4 acc[4][4] = {};
  const bf16* Aseg[2] = { Zb + 256*1024, Hb + 256*1024 };
  #pragma unroll
  for (int seg=0; seg<2; seg++){
    const bf16* A = Aseg[seg];
    const bf16* Wb = W + seg*1024;
    for (int kb=0; kb<1024; kb+=32){
      stage16(A  + (size_t)(m0+r0)*1024 + kb + o0, lA0);
      stage16(A  + (size_t)(m0+r1)*1024 + kb + o1, lA1);
      stage16(Wb + (size_t)(j0+r0)*2048 + kb + o0, lB0);
      stage16(Wb + (size_t)(j0+r1)*2048 + kb + o1, lB1);
      __syncthreads();
      short8 af[4], bfr[4];
      #pragma unroll
      for (int f=0; f<4; f++){
        af[f]  = *(const short8*)&As[swz_rd(mh + f*16 + lr, lq)];
        bfr[f] = *(const short8*)&Bs[swz_rd(jh + f*16 + lr, lq)];
      }
      #pragma unroll
      for (int mf=0; mf<4; mf++)
        #pragma unroll
        for (int jf=0; jf<4; jf++)
          acc[mf][jf] = MFMA16(af[mf], bfr[jf], acc[mf][jf]);
      __syncthreads();
    }
  }
  #pragma unroll
  for (int mf=0; mf<4; mf++)
    #pragma unroll
    for (int jf=0; jf<4; jf++)
      #pragma unroll
      for (int i=0; i<4; i++){
        int m = m0 + mh + mf*16 + lq*4 + i;
        int j = j0 + jh + jf*16 + lr;
        Y[(size_t)m*1024 + j] = __float2bfloat16(ftanh(acc[mf][jf][i] + bias[j]));
      }
}

// grid (128,4)
__global__ __launch_bounds__(256) void k_out1v2(
  const bf16* __restrict__ Yb, const bf16* __restrict__ W,
  const float* __restrict__ bias, float* __restrict__ out)
{
  __shared__ __align__(16) bf16 As[128*32];
  __shared__ __align__(16) bf16 Bs[128*32];
  const int tid = threadIdx.x, lane = tid & 63, w = tid >> 6;
  const int lr = lane & 15, lq = lane >> 4;
  const int mh = (w & 1) * 64, jh = (w >> 1) * 64;
  const int m0 = blockIdx.x * 128, j0 = blockIdx.y * 128;
  const int cA0 = w*128 + lane,      cA1 = w*128 + 64 + lane;
  const int r0 = cA0>>2, o0 = swz_src_off(cA0), r1 = cA1>>2, o1 = swz_src_off(cA1);
  bf16* lA0 = As + (w*2+0)*512; bf16* lA1 = As + (w*2+1)*512;
  bf16* lB0 = Bs + (w*2+0)*512; bf16* lB1 = Bs + (w*2+1)*512;
  floatx4 acc[4][4] = {};
  for (int kb=0; kb<1024; kb+=32){
    stage16(Yb + (size_t)(m0+r0)*1024 + kb + o0, lA0);
    stage16(Yb + (size_t)(m0+r1)*1024 + kb + o1, lA1);
    stage16(W  + (size_t)(j0+r0)*1024 + kb + o0, lB0);
    stage16(W  + (size_t)(j0+r1)*1024 + kb + o1, lB1);
    __syncthreads();
    short8 af[4], bfr[4];
    #pragma unroll
    for (int f=0; f<4; f++){
      af[f]  = *(const short8*)&As[swz_rd(mh + f*16 + lr, lq)];
      bfr[f] = *(const short8*)&Bs[swz_rd(jh + f*16 + lr, lq)];
    }
    #pragma unroll
    for (int mf=0; mf<4; mf++)
      #pragma unroll
      for (int jf=0; jf<4; jf++)
        acc[mf][jf] = MFMA16(af[mf], bfr[jf], acc[mf][jf]);
    __syncthreads();
  }
  #pragma unroll
  for (int mf=0; mf<4; mf++)
    #pragma unroll
    for (int jf=0; jf<4; jf++)
      #pragma unroll
      for (int i=0; i<4; i++){
        int m = m0 + mh + mf*16 + lq*4 + i;
        int j = j0 + jh + jf*16 + lr;
        int b = m & 255, t = m >> 8;
        out[(size_t)b*40960 + t*640 + j] = acc[mf][jf][i] + bias[j];
      }
}

__global__ __launch_bounds__(256) void k_sd(
  const bf16* __restrict__ Zb, const bf16* __restrict__ Hb,
  const bf16* __restrict__ W, const float* __restrict__ bias,
  float* __restrict__ out)
{
  int lane = threadIdx.x & 63, wave = threadIdx.x >> 6;
  int lr = lane & 15, lq = lane >> 4;
  int m0 = blockIdx.x * 32;
  int j0 = wave * 16;
  floatx4 aM[2] = {}, aL[2] = {};
  const bf16* Az = Zb + 256*1024;
  const bf16* Ah = Hb + 256*1024;
  #pragma unroll 2
  for (int kb=0; kb<1024; kb+=32){
    short8 a0 = ldf(Az + (m0+lr)*1024 + kb + lq*8);
    short8 a1 = ldf(Az + (m0+16+lr)*1024 + kb + lq*8);
    short8 bm = ldf(W + (size_t)(j0+lr)*2048 + kb + lq*8);
    short8 bl = ldf(W + (size_t)(j0+64+lr)*2048 + kb + lq*8);
    aM[0] = MFMA16(a0,bm,aM[0]); aM[1] = MFMA16(a1,bm,aM[1]);
    aL[0] = MFMA16(a0,bl,aL[0]); aL[1] = MFMA16(a1,bl,aL[1]);
  }
  #pragma unroll 2
  for (int kb=0; kb<1024; kb+=32){
    short8 a0 = ldf(Ah + (m0+lr)*1024 + kb + lq*8);
    short8 a1 = ldf(Ah + (m0+16+lr)*1024 + kb + lq*8);
    short8 bm = ldf(W + (size_t)(j0+lr)*2048 + 1024 + kb + lq*8);
    short8 bl = ldf(W + (size_t)(j0+64+lr)*2048 + 1024 + kb + lq*8);
    aM[0] = MFMA16(a0,bm,aM[0]); aM[1] = MFMA16(a1,bm,aM[1]);
    aL[0] = MFMA16(a0,bl,aL[0]); aL[1] = MFMA16(a1,bl,aL[1]);
  }
  #pragma unroll
  for (int rf=0;rf<2;rf++)
    #pragma unroll
    for (int i=0;i<4;i++){
      int m = m0 + rf*16 + lq*4 + i;
      int j = j0 + lr;
      int b = m & 255, t = m >> 8;
      out[b*40960 + t*640 + 512 + j] = aM[rf][i] + bias[j];
      out[b*40960 + t*640 + 576 + j] = __expf(aL[rf][i] + bias[64+j]);
    }
}

extern "C" void kernel_launch(void* const* d_in, const int* in_sizes, int n_in,
                              void* d_out, int out_size, void* d_ws, size_t ws_size,
                              hipStream_t stream)
{
  const float* obs    = (const float*)d_in[0];
  const float* state  = (const float*)d_in[1];
  const float* act    = (const float*)d_in[2];
  const float* eps0   = (const float*)d_in[3];
  const float* epss   = (const float*)d_in[4];
  const float* enc_w1 = (const float*)d_in[5];  const float* enc_b1 = (const float*)d_in[6];
  const float* enc_w2 = (const float*)d_in[7];  const float* enc_b2 = (const float*)d_in[8];
  const float* post_w1= (const float*)d_in[9];  const float* post_b1= (const float*)d_in[10];
  const float* post_w2= (const float*)d_in[11]; const float* post_b2= (const float*)d_in[12];
  const float* amlp_w1= (const float*)d_in[13]; const float* amlp_b1= (const float*)d_in[14];
  const float* amlp_w2= (const float*)d_in[15]; const float* amlp_b2= (const float*)d_in[16];
  const float* gwih   = (const float*)d_in[17];
  const float* gwhh   = (const float*)d_in[18];
  const float* gbih   = (const float*)d_in[19];
  const float* gbhh   = (const float*)d_in[20];
  const float* lsd_w1 = (const float*)d_in[21]; const float* lsd_b1 = (const float*)d_in[22];
  const float* lsd_w2 = (const float*)d_in[23]; const float* lsd_b2 = (const float*)d_in[24];
  const float* dec_w1 = (const float*)d_in[25]; const float* dec_b1 = (const float*)d_in[26];
  const float* dec_w2 = (const float*)d_in[27]; const float* dec_b2 = (const float*)d_in[28];
  const float* sd_w   = (const float*)d_in[29]; const float* sd_b   = (const float*)d_in[30];
  float* out = (float*)d_out;

  char* w = (char*)d_ws;
  size_t off = 0;
  auto alloc = [&](size_t elems)->bf16* {
    bf16* p = (bf16*)(w + off);
    off += ((elems*2 + 255)/256)*256;
    return p;
  };
  bf16* WzT      = alloc((size_t)3072*1024);
  bf16* WhT      = alloc((size_t)3072*1024);
  bf16* WaT      = alloc((size_t)3072*512);
  bf16* lsd_w1T  = alloc((size_t)1024*1024);
  bf16* lsd_w2T  = alloc((size_t)2048*1024);
  bf16* dec_w1T  = alloc((size_t)1024*2048);
  bf16* dec_w2T  = alloc((size_t)512*1024);
  bf16* sd_wT    = alloc((size_t)128*2048);
  bf16* enc_w1T  = alloc((size_t)512*512);
  bf16* enc_w2T  = alloc((size_t)256*512);
  bf16* post_w1sT= alloc((size_t)1024*192);
  bf16* post_w2T = alloc((size_t)2048*1024);
  bf16* amlp_w2T = alloc((size_t)512*512);
  bf16* obsb     = alloc((size_t)256*512);
  bf16* E1       = alloc((size_t)256*512);
  bf16* PIN      = alloc((size_t)256*192);
  bf16* P1       = alloc((size_t)256*1024);
  bf16* X        = alloc((size_t)256*1024);
  bf16* Zbuf     = alloc((size_t)65*256*1024);
  bf16* Hbuf     = alloc((size_t)65*256*1024);
  bf16* AEb      = alloc((size_t)16384*512);
  bf16* R        = alloc((size_t)16384*3072);   // union region: H1 / GI / Y1
  bf16* Y1       = R;
  bf16* GI       = R;
  bf16* H1       = R;      // H1 dead before GI written; GI dead before Y1 written
  const bool useGI = (ws_size >= off);

  // --- weight prep: ONE fused transpose launch ---
  TPJobs jobs;
  jobs.src[0]=enc_w1;  jobs.dst[0]=enc_w1T;
  jobs.src[1]=enc_w2;  jobs.dst[1]=enc_w2T;
  jobs.src[2]=post_w1 + (size_t)1024*1024; jobs.dst[2]=post_w1sT;
  jobs.src[3]=post_w2; jobs.dst[3]=post_w2T;
  jobs.src[4]=amlp_w2; jobs.dst[4]=amlp_w2T;
  jobs.src[5]=gwih;    jobs.dst[5]=WzT;
  jobs.src[6]=gwih + (size_t)1024*3072; jobs.dst[6]=WaT;
  jobs.src[7]=gwhh;    jobs.dst[7]=WhT;
  jobs.src[8]=lsd_w1;  jobs.dst[8]=lsd_w1T;
  jobs.src[9]=lsd_w2;  jobs.dst[9]=lsd_w2T;
  jobs.src[10]=dec_w1; jobs.dst[10]=dec_w1T;
  jobs.src[11]=dec_w2; jobs.dst[11]=dec_w2T;
  jobs.src[12]=sd_w;   jobs.dst[12]=sd_wT;
  k_transpose_all<<<16448,256,0,stream>>>(jobs);

  k_cast<<<512,256,0,stream>>>(obs, obsb, 256*512);
  k_cast_state<<<64,256,0,stream>>>(state, PIN);
  k_acth1<<<32768,256,0,stream>>>(act, amlp_w1, amlp_b1, H1);

  hipMemsetAsync(Hbuf, 0, (size_t)256*1024*2, stream);

  k_gemm16<<<dim3(8,16),256,0,stream>>>(obsb, 512, enc_w1T, enc_b1, E1, 512, 0, 512, 1);
  k_gemm16<<<dim3(2,16),256,0,stream>>>(E1, 512, enc_w2T, enc_b2, PIN, 192, 64, 512, 0);
  k_gemm16<<<dim3(16,16),256,0,stream>>>(PIN, 192, post_w1sT, post_b1, P1, 1024, 0, 192, 1);
  k_gauss<<<dim3(16,16),256,0,stream>>>(P1, post_w2T, post_b2, eps0, Zbuf, 1024);
  k_aev2<<<dim3(128,4),256,0,stream>>>(H1, amlp_w2T, amlp_b2, AEb);
  if (useGI)
    k_giv2<<<dim3(128,24),256,0,stream>>>(AEb, WaT, gbih, gbhh, GI);  // overwrites H1 (dead)

  // --- sequential scan: 3 kernels per step (512 blocks each, 32-row m-tiles) ---
  for (int t=0; t<64; t++){
    const bf16* Zt = Zbuf + (size_t)t*262144;
    const bf16* Ht = Hbuf + (size_t)t*262144;
    bf16* Htn = Hbuf + (size_t)(t+1)*262144;
    bf16* Ztn = Zbuf + (size_t)(t+1)*262144;
    if (useGI)
      k_gru3<<<512,256,0,stream>>>(Zt, Ht, GI + (size_t)t*256*3072, WzT, WhT, gbhh, Htn);
    else
      k_gru2<<<1024,256,0,stream>>>(Zt, Ht, AEb + (size_t)t*131072, WzT, WhT, WaT, gbih, gbhh, Htn);
    k_lsd1<<<512,256,0,stream>>>(Htn, lsd_w1T, lsd_b1, X);
    k_lsd2<<<512,256,0,stream>>>(X, lsd_w2T, lsd_b2, epss + (size_t)t*262144, Ztn);
  }

  // --- decode (Y1 overwrites GI region — GI dead after scan) ---
  k_dec1v2<<<dim3(128,8),256,0,stream>>>(Zbuf, Hbuf, dec_w1T, dec_b1, Y1);
  k_out1v2<<<dim3(128,4),256,0,stream>>>(Y1, dec_w2T, dec_b2, out);
  k_sd<<<512,256,0,stream>>>(Zbuf, Hbuf, sd_wT, sd_b, out);
}